// Round 1
// baseline (368.106 us; speedup 1.0000x reference)
//
#include <hip/hip_runtime.h>
#include <math.h>

#define B_  128
#define T_  400
#define E_  128
#define H2_ 256
#define H4_ 512
#define V_  50000
#define G4_ 1024   // 4*H2
#define KACT 384   // E + H2

// output offsets (floats)
#define OFF_H       6400000
#define OFF_C       6432768
#define OFF_ATTN    6465536
#define OFF_COPY    6516736
#define OFF_NEWCOV 12916736
#define OFF_COVLOSS 12967936

// workspace offsets (floats)
#define WS_ACT   0                    // [384][128] act (emb;h0) transposed [k][b]
#define WS_GATES (WS_ACT + KACT*B_)   // [1024][128] gates [j][b]
#define WS_HC    (WS_GATES + G4_*B_)  // [512][128]  (h;ctx) [k][b]
#define WS_FC    (WS_HC + H4_*B_)     // [512][128]  fc [k][b]
#define WS_HDOT  (WS_FC + H4_*B_)     // [128]
#define WS_COVP  (WS_HDOT + B_)       // [128]
#define WS_PGEN  (WS_COVP + B_)       // [128]
#define WS_MAX   (WS_PGEN + B_)       // [128]
#define WS_INV   (WS_MAX + B_)        // [128]

__device__ inline float sigmoidf_(float x){ return 1.f/(1.f+__expf(-x)); }

__device__ inline float blk_reduce_sum(float v, float* red){
  int t = threadIdx.x;
  red[t] = v; __syncthreads();
  for (int s = 128; s > 0; s >>= 1){ if (t < s) red[t] += red[t+s]; __syncthreads(); }
  float r = red[0]; __syncthreads(); return r;
}
__device__ inline float blk_reduce_max(float v, float* red){
  int t = threadIdx.x;
  red[t] = v; __syncthreads();
  for (int s = 128; s > 0; s >>= 1){ if (t < s) red[t] = fmaxf(red[t], red[t+s]); __syncthreads(); }
  float r = red[0]; __syncthreads(); return r;
}

// ---- K0: build act[k][b] = concat(emb, h0) transposed ----
__global__ __launch_bounds__(256) void k_act(const int* __restrict__ ids,
    const float* __restrict__ pre_h, const float* __restrict__ emb_table,
    float* __restrict__ act){
  int idx = blockIdx.x*256 + threadIdx.x;        // 384*128 = 49152
  if (idx >= KACT*B_) return;
  int k = idx >> 7, b = idx & 127;
  float v = (k < E_) ? emb_table[(size_t)ids[b]*E_ + k]
                     : pre_h[b*H2_ + (k - E_)];
  act[idx] = v;
}

// ---- K1: gates[j][b] = w_ih[j]·emb[b] + w_hh[j]·h0[b] + b_ih + b_hh ----
__global__ __launch_bounds__(256) void k_gates(const float* __restrict__ act,
    const float* __restrict__ w_ih, const float* __restrict__ w_hh,
    const float* __restrict__ b_ih, const float* __restrict__ b_hh,
    float* __restrict__ gates){
  __shared__ float wt[8][KACT];   // 12 KB
  int t = threadIdx.x; int j0 = blockIdx.x*8;
  for (int idx = t; idx < 8*KACT; idx += 256) {
    int r = idx / KACT, k = idx % KACT;
    int j = j0 + r;
    wt[r][k] = (k < E_) ? w_ih[j*E_ + k] : w_hh[j*H2_ + (k - E_)];
  }
  __syncthreads();
  int jq = t >> 7, b = t & 127;
  float acc[4] = {0.f,0.f,0.f,0.f};
  for (int k = 0; k < KACT; ++k) {
    float a = act[k*B_ + b];
    #pragma unroll
    for (int jj = 0; jj < 4; ++jj) acc[jj] += wt[jq*4+jj][k]*a;
  }
  #pragma unroll
  for (int jj = 0; jj < 4; ++jj) {
    int j = j0 + jq*4 + jj;
    gates[j*B_ + b] = acc[jj] + b_ih[j] + b_hh[j];
  }
}

// ---- K2: LSTM elementwise + h, c outputs + hdot[b] = h·w_align[256:512] ----
__global__ __launch_bounds__(256) void k_lstm(const float* __restrict__ gates,
    const float* __restrict__ pre_c, const float* __restrict__ w_align,
    float* __restrict__ o_h, float* __restrict__ o_c,
    float* __restrict__ hc, float* __restrict__ hdot){
  __shared__ float red[256];
  int b = blockIdx.x, k = threadIdx.x;
  float i_ = gates[(0*H2_ + k)*B_ + b];
  float f_ = gates[(1*H2_ + k)*B_ + b];
  float g_ = gates[(2*H2_ + k)*B_ + b];
  float o_ = gates[(3*H2_ + k)*B_ + b];
  float c = sigmoidf_(f_)*pre_c[b*H2_ + k] + sigmoidf_(i_)*tanhf(g_);
  float h = sigmoidf_(o_)*tanhf(c);
  o_h[b*H2_ + k] = h;
  o_c[b*H2_ + k] = c;
  hc[k*B_ + b] = h;
  float s = blk_reduce_sum(h * w_align[H2_ + k], red);
  if (k == 0) hdot[b] = s;
}

// ---- K3: attention scores + softmax + newcov + covloss partial + scatter + context ----
__global__ __launch_bounds__(256) void k_attn(const float* __restrict__ enc,
    const float* __restrict__ cov, const int* __restrict__ src,
    const float* __restrict__ w_align, const float* __restrict__ b_align,
    const float* __restrict__ w_cov, const float* __restrict__ b_cov,
    const float* __restrict__ hdot,
    float* __restrict__ o_attn, float* __restrict__ o_newcov,
    float* __restrict__ o_copy, float* __restrict__ covp,
    float* __restrict__ hc){
  __shared__ float sc[T_];
  __shared__ float red[256];
  __shared__ float part[4][256];
  int b = blockIdx.x, t = threadIdx.x;
  // alpha = w_cov·w_align[512:768], beta = b_cov·w_align[512:768]
  float wa = w_align[2*H2_ + t];
  float alpha = blk_reduce_sum(w_cov[t]*wa, red);
  float beta  = blk_reduce_sum(b_cov[t]*wa, red);
  int wave = t >> 6, lane = t & 63;
  float4 wa4 = *(const float4*)&w_align[lane*4];
  float hd = hdot[b], ba = b_align[0];
  for (int tt = wave; tt < T_; tt += 4) {
    const float4* ep = (const float4*)&enc[((size_t)b*T_ + tt)*H2_];
    float4 e4 = ep[lane];
    float d = e4.x*wa4.x + e4.y*wa4.y + e4.z*wa4.z + e4.w*wa4.w;
    #pragma unroll
    for (int m = 32; m >= 1; m >>= 1) d += __shfl_xor(d, m);
    if (lane == 0) sc[tt] = tanhf(d + hd + alpha*cov[b*T_ + tt] + beta + ba);
  }
  __syncthreads();
  float x1 = sc[t];
  float x2 = (t + 256 < T_) ? sc[t + 256] : -1e30f;
  float mx = blk_reduce_max(fmaxf(x1, x2), red);
  float e1 = __expf(x1 - mx);
  float e2 = (t + 256 < T_) ? __expf(x2 - mx) : 0.f;
  float sum = blk_reduce_sum(e1 + e2, red);
  float inv = 1.f/sum;
  float cl = 0.f;
  {
    float a1 = e1*inv; float c1 = cov[b*T_ + t];
    sc[t] = a1;
    o_attn[b*T_ + t] = a1;
    o_newcov[b*T_ + t] = c1 + a1;
    atomicAdd(&o_copy[(size_t)b*V_ + src[b*T_ + t]], a1);
    cl = fminf(a1, c1);
  }
  if (t + 256 < T_) {
    float a2 = e2*inv; float c2 = cov[b*T_ + t + 256];
    sc[t + 256] = a2;
    o_attn[b*T_ + t + 256] = a2;
    o_newcov[b*T_ + t + 256] = c2 + a2;
    atomicAdd(&o_copy[(size_t)b*V_ + src[b*T_ + t + 256]], a2);
    cl += fminf(a2, c2);
  }
  float clsum = blk_reduce_sum(cl, red);
  if (t == 0) covp[b] = clsum;
  __syncthreads();
  // context[b][e] = sum_t attn[t]*enc[b][t][e]
  float4 acc = make_float4(0.f,0.f,0.f,0.f);
  for (int tt = wave; tt < T_; tt += 4) {
    float a = sc[tt];
    const float4* ep = (const float4*)&enc[((size_t)b*T_ + tt)*H2_];
    float4 e4 = ep[lane];
    acc.x += a*e4.x; acc.y += a*e4.y; acc.z += a*e4.z; acc.w += a*e4.w;
  }
  *(float4*)&part[wave][lane*4] = acc;
  __syncthreads();
  float ctx = part[0][t] + part[1][t] + part[2][t] + part[3][t];
  hc[(H2_ + t)*B_ + b] = ctx;
}

// ---- K4: fc[j][b] = tanh(w_fc1[j]·(h;ctx)[b] + b_fc1[j]) ----
__global__ __launch_bounds__(256) void k_fc1(const float* __restrict__ hc,
    const float* __restrict__ w_fc1, const float* __restrict__ b_fc1,
    float* __restrict__ fc){
  __shared__ float wt[16][H4_];   // 32 KB
  int t = threadIdx.x; int j0 = blockIdx.x*16;
  for (int idx = t; idx < 16*H4_; idx += 256) {
    int r = idx >> 9, k = idx & 511;
    wt[r][k] = w_fc1[(j0 + r)*H4_ + k];
  }
  __syncthreads();
  int jq = t >> 7, b = t & 127;
  float acc[8] = {};
  for (int k = 0; k < H4_; ++k) {
    float a = hc[k*B_ + b];
    #pragma unroll
    for (int jj = 0; jj < 8; ++jj) acc[jj] += wt[jq*8+jj][k]*a;
  }
  #pragma unroll
  for (int jj = 0; jj < 8; ++jj) {
    int j = j0 + jq*8 + jj;
    fc[j*B_ + b] = tanhf(acc[jj] + b_fc1[j]);
  }
}

// ---- K_pgen: pgen[b] = sigmoid(w_gen·[ctx;h;emb] + b_gen) ----
__global__ __launch_bounds__(256) void k_pgen(const float* __restrict__ hc,
    const int* __restrict__ ids, const float* __restrict__ emb_table,
    const float* __restrict__ w_gen, const float* __restrict__ b_gen,
    float* __restrict__ pgen){
  __shared__ float red[256];
  int b = blockIdx.x, t = threadIdx.x;
  float p = hc[(H2_ + t)*B_ + b] * w_gen[t]          // context part
          + hc[t*B_ + b]         * w_gen[H2_ + t];   // h part
  if (t < E_) p += emb_table[(size_t)ids[b]*E_ + t] * w_gen[2*H2_ + t];
  float s = blk_reduce_sum(p, red);
  if (t == 0) pgen[b] = sigmoidf_(s + b_gen[0]);
}

// ---- K_cl: deterministic covloss reduce ----
__global__ void k_covloss(const float* __restrict__ covp, float* __restrict__ o_cl){
  __shared__ float red[128];
  int t = threadIdx.x;
  red[t] = covp[t]; __syncthreads();
  for (int s = 64; s > 0; s >>= 1){ if (t < s) red[t] += red[t+s]; __syncthreads(); }
  if (t == 0) o_cl[0] = red[0];
}

// ---- K5: logits[b][v] = fc[b]·w_fc2[v] + b_fc2[v], 128v x 128b tile per block ----
#define VT 128
#define BK 64
__global__ __launch_bounds__(256) void k_gemm2(const float* __restrict__ fc,
    const float* __restrict__ w_fc2, const float* __restrict__ b_fc2,
    float* __restrict__ logits){
  __shared__ float wt[BK][VT];    // 32 KB, [k][v]
  __shared__ float at[BK][B_];    // 32 KB, [k][b]
  int t = threadIdx.x;
  int v0 = blockIdx.x * VT;
  int vg = t >> 4, bg = t & 15;
  float acc[8][8] = {};
  for (int kc = 0; kc < H4_; kc += BK) {
    __syncthreads();
    #pragma unroll
    for (int r = 0; r < 8; ++r) {            // stage w tile (transposed)
      int q = t + 256*r;                     // 2048 float4s
      int vv = q >> 4, kk = q & 15;
      int v = v0 + vv;
      float4 w4 = (v < V_) ? *(const float4*)&w_fc2[(size_t)v*H4_ + kc + kk*4]
                           : make_float4(0.f,0.f,0.f,0.f);
      wt[kk*4+0][vv] = w4.x; wt[kk*4+1][vv] = w4.y;
      wt[kk*4+2][vv] = w4.z; wt[kk*4+3][vv] = w4.w;
    }
    #pragma unroll
    for (int r = 0; r < 8; ++r) {            // stage fc tile (already [k][b])
      int off = (t + 256*r)*4;
      *(float4*)&((float*)at)[off] = *(const float4*)&fc[kc*B_ + off];
    }
    __syncthreads();
    for (int k = 0; k < BK; ++k) {
      float4 w0 = *(float4*)&wt[k][vg*8];
      float4 w1 = *(float4*)&wt[k][vg*8+4];
      float4 a0 = *(float4*)&at[k][bg*8];
      float4 a1 = *(float4*)&at[k][bg*8+4];
      float wv[8] = {w0.x,w0.y,w0.z,w0.w,w1.x,w1.y,w1.z,w1.w};
      float av[8] = {a0.x,a0.y,a0.z,a0.w,a1.x,a1.y,a1.z,a1.w};
      #pragma unroll
      for (int i = 0; i < 8; ++i)
        #pragma unroll
        for (int j = 0; j < 8; ++j) acc[i][j] += wv[i]*av[j];
    }
  }
  #pragma unroll
  for (int j = 0; j < 8; ++j) {
    int b = bg*8 + j;
    #pragma unroll
    for (int i = 0; i < 8; i += 4) {
      int v = v0 + vg*8 + i;
      if (v + 3 < V_) {
        float4 o;
        o.x = acc[i+0][j] + b_fc2[v+0];
        o.y = acc[i+1][j] + b_fc2[v+1];
        o.z = acc[i+2][j] + b_fc2[v+2];
        o.w = acc[i+3][j] + b_fc2[v+3];
        *(float4*)&logits[(size_t)b*V_ + v] = o;
      } else {
        for (int ii = i; ii < i+4; ++ii) {
          int vv2 = v0 + vg*8 + ii;
          if (vv2 < V_) logits[(size_t)b*V_ + vv2] = acc[ii][j] + b_fc2[vv2];
        }
      }
    }
  }
}

// ---- K6: per-b online softmax stats over V ----
__global__ __launch_bounds__(256) void k_smstats(const float* __restrict__ logits,
    float* __restrict__ mxo, float* __restrict__ invo){
  __shared__ float rm[256], rs[256];
  int b = blockIdx.x, t = threadIdx.x;
  float m = -1e30f, s = 0.f;
  for (int v = t; v < V_; v += 256) {
    float x = logits[(size_t)b*V_ + v];
    float nm = fmaxf(m, x);
    s = s*__expf(m - nm) + __expf(x - nm);
    m = nm;
  }
  rm[t] = m; rs[t] = s; __syncthreads();
  for (int k = 128; k > 0; k >>= 1) {
    if (t < k) {
      float m1 = rm[t], s1 = rs[t], m2 = rm[t+k], s2 = rs[t+k];
      float nm = fmaxf(m1, m2);
      rm[t] = nm; rs[t] = s1*__expf(m1-nm) + s2*__expf(m2-nm);
    }
    __syncthreads();
  }
  if (t == 0) { mxo[b] = rm[0]; invo[b] = 1.f/rs[0]; }
}

// ---- K7: out = softmax(logit)*pgen + copy*(1-pgen), in place over logits ----
__global__ __launch_bounds__(256) void k_final(const float* __restrict__ copy,
    const float* __restrict__ mx, const float* __restrict__ inv_s,
    const float* __restrict__ pgen, float* __restrict__ out){
  size_t gid = (size_t)blockIdx.x*256 + threadIdx.x;
  if (gid >= (size_t)B_*V_/2) return;
  int b = (int)(gid / (V_/2));
  int v = (int)(gid % (V_/2))*2;
  size_t idx = (size_t)b*V_ + v;
  float m = mx[b], is = inv_s[b], pg = pgen[b];
  float2 lg = *(const float2*)&out[idx];
  float2 cp = *(const float2*)&copy[idx];
  float2 o;
  o.x = __expf(lg.x - m)*is*pg + cp.x*(1.f - pg);
  o.y = __expf(lg.y - m)*is*pg + cp.y*(1.f - pg);
  *(float2*)&out[idx] = o;
}

extern "C" void kernel_launch(void* const* d_in, const int* in_sizes, int n_in,
                              void* d_out, int out_size, void* d_ws, size_t ws_size,
                              hipStream_t stream) {
  const int*   ids       = (const int*)  d_in[0];
  const float* pre_h     = (const float*)d_in[1];
  const float* pre_c     = (const float*)d_in[2];
  const float* enc       = (const float*)d_in[3];
  const int*   src       = (const int*)  d_in[4];
  const float* cov       = (const float*)d_in[5];
  const float* emb_table = (const float*)d_in[6];
  const float* w_ih      = (const float*)d_in[7];
  const float* w_hh      = (const float*)d_in[8];
  const float* b_ih      = (const float*)d_in[9];
  const float* b_hh      = (const float*)d_in[10];
  const float* w_align   = (const float*)d_in[11];
  const float* b_align   = (const float*)d_in[12];
  const float* w_cov     = (const float*)d_in[13];
  const float* b_cov     = (const float*)d_in[14];
  const float* w_fc1     = (const float*)d_in[15];
  const float* b_fc1     = (const float*)d_in[16];
  const float* w_fc2     = (const float*)d_in[17];
  const float* b_fc2     = (const float*)d_in[18];
  const float* w_gen     = (const float*)d_in[19];
  const float* b_gen     = (const float*)d_in[20];

  float* out = (float*)d_out;
  float* ws  = (float*)d_ws;

  float* o_out    = out;               // logits first, then final out in place
  float* o_h      = out + OFF_H;
  float* o_c      = out + OFF_C;
  float* o_attn   = out + OFF_ATTN;
  float* o_copy   = out + OFF_COPY;
  float* o_newcov = out + OFF_NEWCOV;
  float* o_cl     = out + OFF_COVLOSS;

  hipMemsetAsync(o_copy, 0, (size_t)B_*V_*sizeof(float), stream);

  k_act  <<<192, 256, 0, stream>>>(ids, pre_h, emb_table, ws + WS_ACT);
  k_gates<<<128, 256, 0, stream>>>(ws + WS_ACT, w_ih, w_hh, b_ih, b_hh, ws + WS_GATES);
  k_lstm <<<128, 256, 0, stream>>>(ws + WS_GATES, pre_c, w_align, o_h, o_c,
                                   ws + WS_HC, ws + WS_HDOT);
  k_attn <<<128, 256, 0, stream>>>(enc, cov, src, w_align, b_align, w_cov, b_cov,
                                   ws + WS_HDOT, o_attn, o_newcov, o_copy,
                                   ws + WS_COVP, ws + WS_HC);
  k_fc1  <<<32, 256, 0, stream>>>(ws + WS_HC, w_fc1, b_fc1, ws + WS_FC);
  k_pgen <<<128, 256, 0, stream>>>(ws + WS_HC, ids, emb_table, w_gen, b_gen,
                                   ws + WS_PGEN);
  k_covloss<<<1, 128, 0, stream>>>(ws + WS_COVP, o_cl);
  k_gemm2<<<(V_ + VT - 1)/VT, 256, 0, stream>>>(ws + WS_FC, w_fc2, b_fc2, o_out);
  k_smstats<<<128, 256, 0, stream>>>(o_out, ws + WS_MAX, ws + WS_INV);
  k_final<<<(int)(((size_t)B_*V_/2 + 255)/256), 256, 0, stream>>>(
      o_copy, ws + WS_MAX, ws + WS_INV, ws + WS_PGEN, o_out);
}

// Round 2
// 203.927 us; speedup vs baseline: 1.8051x; 1.8051x over previous
//
#include <hip/hip_runtime.h>
#include <hip/hip_bf16.h>
#include <math.h>

#define B_  128
#define T_  400
#define E_  128
#define H2_ 256
#define H4_ 512
#define V_  50000
#define G4_ 1024   // 4*H2
#define KACT 384   // E + H2

// output offsets (floats)
#define OFF_H       6400000
#define OFF_C       6432768
#define OFF_ATTN    6465536
#define OFF_COPY    6516736
#define OFF_NEWCOV 12916736
#define OFF_COVLOSS 12967936

// workspace offsets (floats)
#define WS_ACT   0                      // [384][128] act (emb;h0) [k][b]
#define WS_GATES (WS_ACT + KACT*B_)     // [1024][128] gates [j][b]
#define WS_HC    (WS_GATES + G4_*B_)    // [512][128]  (h;ctx) [k][b]
#define WS_FCB   (WS_HC + H4_*B_)       // [128][512]  fc bf16 [b][k] (32768 floats)
#define WS_SC    (WS_FCB + H4_*B_/2)    // [128][400]  scores
#define WS_ATTN  (WS_SC + B_*T_)        // [128][400]  attn
#define WS_CTXP  (WS_ATTN + B_*T_)      // [128][8][256] context partials
#define WS_SMP   (WS_CTXP + B_*8*H2_)   // [128][8][2] softmax partials
#define WS_HDOT  (WS_SMP + B_*8*2)      // [128]
#define WS_COVP  (WS_HDOT + B_)         // [128]
#define WS_PGEN  (WS_COVP + B_)         // [128]
#define WS_MAX   (WS_PGEN + B_)         // [128]
#define WS_INV   (WS_MAX + B_)          // [128]
#define WS_AB    (WS_INV + B_)          // [2] alpha, beta

typedef __attribute__((ext_vector_type(8))) short bf16x8;
typedef __attribute__((ext_vector_type(4))) float f32x4;

__device__ inline float sigmoidf_(float x){ return 1.f/(1.f+__expf(-x)); }

__device__ inline short f2bf(float x){
  __hip_bfloat16 h = __float2bfloat16(x);
  return *reinterpret_cast<short*>(&h);
}

__device__ inline float blk_reduce_sum(float v, float* red){
  int t = threadIdx.x;
  red[t] = v; __syncthreads();
  for (int s = 128; s > 0; s >>= 1){ if (t < s) red[t] += red[t+s]; __syncthreads(); }
  float r = red[0]; __syncthreads(); return r;
}
__device__ inline float blk_reduce_max(float v, float* red){
  int t = threadIdx.x;
  red[t] = v; __syncthreads();
  for (int s = 128; s > 0; s >>= 1){ if (t < s) red[t] = fmaxf(red[t], red[t+s]); __syncthreads(); }
  float r = red[0]; __syncthreads(); return r;
}

// ---- K0: act[k][b] = concat(emb,h0) transposed; block 0 also computes alpha/beta ----
__global__ __launch_bounds__(256) void k_act(const int* __restrict__ ids,
    const float* __restrict__ pre_h, const float* __restrict__ emb_table,
    const float* __restrict__ w_align, const float* __restrict__ w_cov,
    const float* __restrict__ b_cov, float* __restrict__ act,
    float* __restrict__ ab){
  __shared__ float red[256];
  int t = threadIdx.x;
  int idx = blockIdx.x*256 + t;
  int k = idx >> 7, b = idx & 127;
  float v = (k < E_) ? emb_table[(size_t)ids[b]*E_ + k]
                     : pre_h[b*H2_ + (k - E_)];
  act[idx] = v;
  if (blockIdx.x == 0) {
    float wa = w_align[2*H2_ + t];
    float alpha = blk_reduce_sum(w_cov[t]*wa, red);
    float beta  = blk_reduce_sum(b_cov[t]*wa, red);
    if (t == 0) { ab[0] = alpha; ab[1] = beta; }
  }
}

// ---- K1: gates[j][b] ----
__global__ __launch_bounds__(256) void k_gates(const float* __restrict__ act,
    const float* __restrict__ w_ih, const float* __restrict__ w_hh,
    const float* __restrict__ b_ih, const float* __restrict__ b_hh,
    float* __restrict__ gates){
  __shared__ float wt[8][KACT];
  int t = threadIdx.x; int j0 = blockIdx.x*8;
  for (int idx = t; idx < 8*KACT; idx += 256) {
    int r = idx / KACT, k = idx % KACT;
    int j = j0 + r;
    wt[r][k] = (k < E_) ? w_ih[j*E_ + k] : w_hh[j*H2_ + (k - E_)];
  }
  __syncthreads();
  int jq = t >> 7, b = t & 127;
  float acc[4] = {0.f,0.f,0.f,0.f};
  for (int k = 0; k < KACT; ++k) {
    float a = act[k*B_ + b];
    #pragma unroll
    for (int jj = 0; jj < 4; ++jj) acc[jj] += wt[jq*4+jj][k]*a;
  }
  #pragma unroll
  for (int jj = 0; jj < 4; ++jj) {
    int j = j0 + jq*4 + jj;
    gates[j*B_ + b] = acc[jj] + b_ih[j] + b_hh[j];
  }
}

// ---- K2: LSTM elementwise + hdot ----
__global__ __launch_bounds__(256) void k_lstm(const float* __restrict__ gates,
    const float* __restrict__ pre_c, const float* __restrict__ w_align,
    float* __restrict__ o_h, float* __restrict__ o_c,
    float* __restrict__ hc, float* __restrict__ hdot){
  __shared__ float red[256];
  int b = blockIdx.x, k = threadIdx.x;
  float i_ = gates[(0*H2_ + k)*B_ + b];
  float f_ = gates[(1*H2_ + k)*B_ + b];
  float g_ = gates[(2*H2_ + k)*B_ + b];
  float o_ = gates[(3*H2_ + k)*B_ + b];
  float c = sigmoidf_(f_)*pre_c[b*H2_ + k] + sigmoidf_(i_)*tanhf(g_);
  float h = sigmoidf_(o_)*tanhf(c);
  o_h[b*H2_ + k] = h;
  o_c[b*H2_ + k] = c;
  hc[k*B_ + b] = h;
  float s = blk_reduce_sum(h * w_align[H2_ + k], red);
  if (k == 0) hdot[b] = s;
}

// ---- K3a: scores, grid (8 chunks of 50, B) ----
__global__ __launch_bounds__(256) void k_scores(const float* __restrict__ enc,
    const float* __restrict__ cov, const float* __restrict__ w_align,
    const float* __restrict__ b_align, const float* __restrict__ hdot,
    const float* __restrict__ ab, float* __restrict__ sc){
  int b = blockIdx.y, c = blockIdx.x;
  int t = threadIdx.x, wave = t >> 6, lane = t & 63;
  float4 wa4 = *(const float4*)&w_align[lane*4];
  float hd = hdot[b], alpha = ab[0], beta = ab[1], ba = b_align[0];
  int t0 = c*50;
  for (int tt = t0 + wave; tt < t0 + 50; tt += 4) {
    const float4* ep = (const float4*)&enc[((size_t)b*T_ + tt)*H2_];
    float4 e4 = ep[lane];
    float d = e4.x*wa4.x + e4.y*wa4.y + e4.z*wa4.z + e4.w*wa4.w;
    #pragma unroll
    for (int m = 32; m >= 1; m >>= 1) d += __shfl_xor(d, m);
    if (lane == 0)
      sc[b*T_ + tt] = tanhf(d + hd + alpha*cov[b*T_ + tt] + beta + ba);
  }
}

// ---- K3b: softmax over T + scatter + newcov + covloss partial ----
__global__ __launch_bounds__(256) void k_soft(const float* __restrict__ sc_in,
    const float* __restrict__ cov, const int* __restrict__ src,
    float* __restrict__ o_attn, float* __restrict__ o_newcov,
    float* __restrict__ o_copy, float* __restrict__ covp,
    float* __restrict__ attn_ws){
  __shared__ float red[256];
  int b = blockIdx.x, t = threadIdx.x;
  float x1 = sc_in[b*T_ + t];
  float x2 = (t + 256 < T_) ? sc_in[b*T_ + t + 256] : -1e30f;
  float mx = blk_reduce_max(fmaxf(x1, x2), red);
  float e1 = __expf(x1 - mx);
  float e2 = (t + 256 < T_) ? __expf(x2 - mx) : 0.f;
  float sum = blk_reduce_sum(e1 + e2, red);
  float inv = 1.f/sum;
  float cl;
  {
    float a1 = e1*inv; float c1 = cov[b*T_ + t];
    attn_ws[b*T_ + t] = a1;
    o_attn[b*T_ + t] = a1;
    o_newcov[b*T_ + t] = c1 + a1;
    atomicAdd(&o_copy[(size_t)b*V_ + src[b*T_ + t]], a1);
    cl = fminf(a1, c1);
  }
  if (t + 256 < T_) {
    float a2 = e2*inv; float c2 = cov[b*T_ + t + 256];
    attn_ws[b*T_ + t + 256] = a2;
    o_attn[b*T_ + t + 256] = a2;
    o_newcov[b*T_ + t + 256] = c2 + a2;
    atomicAdd(&o_copy[(size_t)b*V_ + src[b*T_ + t + 256]], a2);
    cl += fminf(a2, c2);
  }
  float clsum = blk_reduce_sum(cl, red);
  if (t == 0) covp[b] = clsum;
}

// ---- K3c: context partials, grid (8 chunks, B) ----
__global__ __launch_bounds__(256) void k_ctx(const float* __restrict__ enc,
    const float* __restrict__ attn_ws, float* __restrict__ ctxp){
  __shared__ float a_s[50];
  int b = blockIdx.y, c = blockIdx.x, e = threadIdx.x;
  int t0 = c*50;
  if (e < 50) a_s[e] = attn_ws[b*T_ + t0 + e];
  __syncthreads();
  float acc = 0.f;
  #pragma unroll 5
  for (int i = 0; i < 50; ++i)
    acc += a_s[i] * enc[((size_t)b*T_ + t0 + i)*H2_ + e];
  ctxp[((size_t)b*8 + c)*H2_ + e] = acc;
}

// ---- K3d: context reduce + pgen ----
__global__ __launch_bounds__(256) void k_ctxpgen(const float* __restrict__ ctxp,
    const int* __restrict__ ids, const float* __restrict__ emb_table,
    const float* __restrict__ w_gen, const float* __restrict__ b_gen,
    float* __restrict__ hc, float* __restrict__ pgen){
  __shared__ float red[256];
  int b = blockIdx.x, t = threadIdx.x;
  float ctx = 0.f;
  #pragma unroll
  for (int c = 0; c < 8; ++c) ctx += ctxp[((size_t)b*8 + c)*H2_ + t];
  hc[(H2_ + t)*B_ + b] = ctx;
  float p = ctx*w_gen[t] + hc[t*B_ + b]*w_gen[H2_ + t];
  if (t < E_) p += emb_table[(size_t)ids[b]*E_ + t]*w_gen[2*H2_ + t];
  float s = blk_reduce_sum(p, red);
  if (t == 0) pgen[b] = sigmoidf_(s + b_gen[0]);
}

// ---- K4: fc1, output bf16 [b][k] ----
__global__ __launch_bounds__(256) void k_fc1(const float* __restrict__ hc,
    const float* __restrict__ w_fc1, const float* __restrict__ b_fc1,
    short* __restrict__ fcb){
  __shared__ float wt[16][H4_];
  int t = threadIdx.x; int j0 = blockIdx.x*16;
  for (int idx = t; idx < 16*H4_; idx += 256) {
    int r = idx >> 9, k = idx & 511;
    wt[r][k] = w_fc1[(j0 + r)*H4_ + k];
  }
  __syncthreads();
  int jq = t >> 7, b = t & 127;
  float acc[8] = {};
  for (int k = 0; k < H4_; ++k) {
    float a = hc[k*B_ + b];
    #pragma unroll
    for (int jj = 0; jj < 8; ++jj) acc[jj] += wt[jq*8+jj][k]*a;
  }
  bf16x8 pack;
  #pragma unroll
  for (int jj = 0; jj < 8; ++jj) {
    int j = j0 + jq*8 + jj;
    pack[jj] = f2bf(tanhf(acc[jj] + b_fc1[j]));
  }
  *(bf16x8*)&fcb[(size_t)b*H4_ + j0 + jq*8] = pack;
}

// ---- K5: MFMA bf16 GEMM. D[b][v] = fcb[b][:]·w_fc2[v][:] ----
// A = fcb (M=b), B = w_fc2 converted in-register (N=v). 64 v per block, 4 waves.
__global__ __launch_bounds__(256) void k_gemm2m(const short* __restrict__ fcb,
    const float* __restrict__ w_fc2, const float* __restrict__ b_fc2,
    float* __restrict__ logits){
  int t = threadIdx.x;
  int w = t >> 6, l = t & 63;
  int lo = l & 15, g = l >> 4;
  int v = blockIdx.x*64 + w*16 + lo;
  int vc = v < V_ ? v : V_ - 1;
  f32x4 acc[8] = {};
  for (int k0 = 0; k0 < H4_; k0 += 32) {
    const float* wp = &w_fc2[(size_t)vc*H4_ + k0 + g*8];
    float4 wA = *(const float4*)wp;
    float4 wB = *(const float4*)(wp + 4);
    bf16x8 bf;
    bf[0] = f2bf(wA.x); bf[1] = f2bf(wA.y); bf[2] = f2bf(wA.z); bf[3] = f2bf(wA.w);
    bf[4] = f2bf(wB.x); bf[5] = f2bf(wB.y); bf[6] = f2bf(wB.z); bf[7] = f2bf(wB.w);
    #pragma unroll
    for (int bg = 0; bg < 8; ++bg) {
      bf16x8 af = *(const bf16x8*)&fcb[(size_t)(bg*16 + lo)*H4_ + k0 + g*8];
      acc[bg] = __builtin_amdgcn_mfma_f32_16x16x32_bf16(af, bf, acc[bg], 0, 0, 0);
    }
  }
  if (v < V_) {
    float bias = b_fc2[v];
    #pragma unroll
    for (int bg = 0; bg < 8; ++bg) {
      #pragma unroll
      for (int r = 0; r < 4; ++r) {
        int b = bg*16 + g*4 + r;
        logits[(size_t)b*V_ + v] = acc[bg][r] + bias;
      }
    }
  }
}

// ---- K6a: softmax partial stats, grid (8, B) ----
__global__ __launch_bounds__(256) void k_smp(const float* __restrict__ logits,
    float* __restrict__ smp){
  __shared__ float rm[256], rs[256];
  int b = blockIdx.y, c = blockIdx.x, t = threadIdx.x;
  int v0 = c*6250, v1 = v0 + 6250;
  float m = -1e30f, s = 0.f;
  for (int v = v0 + t; v < v1; v += 256) {
    float x = logits[(size_t)b*V_ + v];
    float nm = fmaxf(m, x);
    s = s*__expf(m - nm) + __expf(x - nm);
    m = nm;
  }
  rm[t] = m; rs[t] = s; __syncthreads();
  for (int k = 128; k > 0; k >>= 1) {
    if (t < k) {
      float m1 = rm[t], s1 = rs[t], m2 = rm[t+k], s2 = rs[t+k];
      float nm = fmaxf(m1, m2);
      rm[t] = nm; rs[t] = s1*__expf(m1-nm) + s2*__expf(m2-nm);
    }
    __syncthreads();
  }
  if (t == 0) { smp[(b*8+c)*2] = rm[0]; smp[(b*8+c)*2+1] = rs[0]; }
}

// ---- K6b: combine stats + covloss ----
__global__ __launch_bounds__(128) void k_smred_cl(const float* __restrict__ smp,
    const float* __restrict__ covp, float* __restrict__ mx,
    float* __restrict__ inv, float* __restrict__ o_cl){
  __shared__ float red[128];
  int t = threadIdx.x;
  float m = -1e30f, s = 0.f;
  #pragma unroll
  for (int c = 0; c < 8; ++c) {
    float m2 = smp[(t*8+c)*2], s2 = smp[(t*8+c)*2+1];
    float nm = fmaxf(m, m2);
    s = s*__expf(m - nm) + s2*__expf(m2 - nm);
    m = nm;
  }
  mx[t] = m; inv[t] = 1.f/s;
  red[t] = covp[t]; __syncthreads();
  for (int k = 64; k > 0; k >>= 1){ if (t < k) red[t] += red[t+k]; __syncthreads(); }
  if (t == 0) o_cl[0] = red[0];
}

// ---- K7: final mix ----
__global__ __launch_bounds__(256) void k_final(const float* __restrict__ copy,
    const float* __restrict__ mx, const float* __restrict__ inv_s,
    const float* __restrict__ pgen, float* __restrict__ out){
  size_t gid = (size_t)blockIdx.x*256 + threadIdx.x;
  int b = (int)(gid / (V_/2));
  int v = (int)(gid % (V_/2))*2;
  size_t idx = (size_t)b*V_ + v;
  float m = mx[b], is = inv_s[b], pg = pgen[b];
  float2 lg = *(const float2*)&out[idx];
  float2 cp = *(const float2*)&copy[idx];
  float2 o;
  o.x = __expf(lg.x - m)*is*pg + cp.x*(1.f - pg);
  o.y = __expf(lg.y - m)*is*pg + cp.y*(1.f - pg);
  *(float2*)&out[idx] = o;
}

extern "C" void kernel_launch(void* const* d_in, const int* in_sizes, int n_in,
                              void* d_out, int out_size, void* d_ws, size_t ws_size,
                              hipStream_t stream) {
  const int*   ids       = (const int*)  d_in[0];
  const float* pre_h     = (const float*)d_in[1];
  const float* pre_c     = (const float*)d_in[2];
  const float* enc       = (const float*)d_in[3];
  const int*   src       = (const int*)  d_in[4];
  const float* cov       = (const float*)d_in[5];
  const float* emb_table = (const float*)d_in[6];
  const float* w_ih      = (const float*)d_in[7];
  const float* w_hh      = (const float*)d_in[8];
  const float* b_ih      = (const float*)d_in[9];
  const float* b_hh      = (const float*)d_in[10];
  const float* w_align   = (const float*)d_in[11];
  const float* b_align   = (const float*)d_in[12];
  const float* w_cov     = (const float*)d_in[13];
  const float* b_cov     = (const float*)d_in[14];
  const float* w_fc1     = (const float*)d_in[15];
  const float* b_fc1     = (const float*)d_in[16];
  const float* w_fc2     = (const float*)d_in[17];
  const float* b_fc2     = (const float*)d_in[18];
  const float* w_gen     = (const float*)d_in[19];
  const float* b_gen     = (const float*)d_in[20];

  float* out = (float*)d_out;
  float* ws  = (float*)d_ws;

  float* o_out    = out;
  float* o_h      = out + OFF_H;
  float* o_c      = out + OFF_C;
  float* o_attn   = out + OFF_ATTN;
  float* o_copy   = out + OFF_COPY;
  float* o_newcov = out + OFF_NEWCOV;
  float* o_cl     = out + OFF_COVLOSS;

  hipMemsetAsync(o_copy, 0, (size_t)B_*V_*sizeof(float), stream);

  k_act  <<<192, 256, 0, stream>>>(ids, pre_h, emb_table, w_align, w_cov, b_cov,
                                   ws + WS_ACT, ws + WS_AB);
  k_gates<<<128, 256, 0, stream>>>(ws + WS_ACT, w_ih, w_hh, b_ih, b_hh, ws + WS_GATES);
  k_lstm <<<128, 256, 0, stream>>>(ws + WS_GATES, pre_c, w_align, o_h, o_c,
                                   ws + WS_HC, ws + WS_HDOT);
  k_scores<<<dim3(8,128), 256, 0, stream>>>(enc, cov, w_align, b_align,
                                   ws + WS_HDOT, ws + WS_AB, ws + WS_SC);
  k_soft <<<128, 256, 0, stream>>>(ws + WS_SC, cov, src, o_attn, o_newcov, o_copy,
                                   ws + WS_COVP, ws + WS_ATTN);
  k_ctx  <<<dim3(8,128), 256, 0, stream>>>(enc, ws + WS_ATTN, ws + WS_CTXP);
  k_ctxpgen<<<128, 256, 0, stream>>>(ws + WS_CTXP, ids, emb_table, w_gen, b_gen,
                                   ws + WS_HC, ws + WS_PGEN);
  k_fc1  <<<32, 256, 0, stream>>>(ws + WS_HC, w_fc1, b_fc1, (short*)(ws + WS_FCB));
  k_gemm2m<<<(V_ + 63)/64, 256, 0, stream>>>((const short*)(ws + WS_FCB),
                                   w_fc2, b_fc2, o_out);
  k_smp  <<<dim3(8,128), 256, 0, stream>>>(o_out, ws + WS_SMP);
  k_smred_cl<<<1, 128, 0, stream>>>(ws + WS_SMP, ws + WS_COVP,
                                   ws + WS_MAX, ws + WS_INV, o_cl);
  k_final<<<(int)(((size_t)B_*V_/2)/256), 256, 0, stream>>>(
      o_copy, ws + WS_MAX, ws + WS_INV, ws + WS_PGEN, o_out);
}

// Round 3
// 154.297 us; speedup vs baseline: 2.3857x; 1.3217x over previous
//
#include <hip/hip_runtime.h>
#include <hip/hip_bf16.h>
#include <math.h>

#define B_  128
#define T_  400
#define E_  128
#define H2_ 256
#define H4_ 512
#define V_  50000
#define G4_ 1024   // 4*H2
#define KACT 384   // E + H2

// output offsets (floats)
#define OFF_H       6400000
#define OFF_C       6432768
#define OFF_ATTN    6465536
#define OFF_COPY    6516736
#define OFF_NEWCOV 12916736
#define OFF_COVLOSS 12967936

// workspace offsets (floats)
#define WS_ACT   0                      // [384][128] act (emb;h0) [k][b]
#define WS_GATES (WS_ACT + KACT*B_)     // [1024][128] gates [j][b]
#define WS_HC    (WS_GATES + G4_*B_)    // [512][128]  (h;ctx) [k][b]
#define WS_FCB   (WS_HC + H4_*B_)       // [128][512]  fc bf16 [b][k] (32768 floats)
#define WS_SC    (WS_FCB + H4_*B_/2)    // [128][400]  scores
#define WS_ATTN  (WS_SC + B_*T_)        // [128][400]  attn
#define WS_CTXP  (WS_ATTN + B_*T_)      // [128][8][256] context partials
#define WS_SMP   (WS_CTXP + B_*8*H2_)   // [128][8][2] softmax partials
#define WS_HDOT  (WS_SMP + B_*8*2)      // [128]
#define WS_COVP  (WS_HDOT + B_)         // [128]
#define WS_PGEN  (WS_COVP + B_)         // [128]
#define WS_MAX   (WS_PGEN + B_)         // [128]
#define WS_INV   (WS_MAX + B_)          // [128]
#define WS_AB    (WS_INV + B_)          // [2] alpha, beta

typedef __attribute__((ext_vector_type(8))) short bf16x8;
typedef __attribute__((ext_vector_type(4))) float f32x4;

__device__ inline float sigmoidf_(float x){ return 1.f/(1.f+__expf(-x)); }

__device__ inline short f2bf(float x){
  __hip_bfloat16 h = __float2bfloat16(x);
  return *reinterpret_cast<short*>(&h);
}

__device__ inline float blk_reduce_sum(float v, float* red){
  int t = threadIdx.x;
  red[t] = v; __syncthreads();
  for (int s = 128; s > 0; s >>= 1){ if (t < s) red[t] += red[t+s]; __syncthreads(); }
  float r = red[0]; __syncthreads(); return r;
}
__device__ inline float blk_reduce_max(float v, float* red){
  int t = threadIdx.x;
  red[t] = v; __syncthreads();
  for (int s = 128; s > 0; s >>= 1){ if (t < s) red[t] = fmaxf(red[t], red[t+s]); __syncthreads(); }
  float r = red[0]; __syncthreads(); return r;
}

// ---- K0: act[k][b] = concat(emb,h0) transposed; block 0 also computes alpha/beta ----
__global__ __launch_bounds__(256) void k_act(const int* __restrict__ ids,
    const float* __restrict__ pre_h, const float* __restrict__ emb_table,
    const float* __restrict__ w_align, const float* __restrict__ w_cov,
    const float* __restrict__ b_cov, float* __restrict__ act,
    float* __restrict__ ab){
  __shared__ float red[256];
  int t = threadIdx.x;
  int idx = blockIdx.x*256 + t;
  int k = idx >> 7, b = idx & 127;
  float v = (k < E_) ? emb_table[(size_t)ids[b]*E_ + k]
                     : pre_h[b*H2_ + (k - E_)];
  act[idx] = v;
  if (blockIdx.x == 0) {
    float wa = w_align[2*H2_ + t];
    float alpha = blk_reduce_sum(w_cov[t]*wa, red);
    float beta  = blk_reduce_sum(b_cov[t]*wa, red);
    if (t == 0) { ab[0] = alpha; ab[1] = beta; }
  }
}

// ---- K1: gates[j][b] ----
__global__ __launch_bounds__(256) void k_gates(const float* __restrict__ act,
    const float* __restrict__ w_ih, const float* __restrict__ w_hh,
    const float* __restrict__ b_ih, const float* __restrict__ b_hh,
    float* __restrict__ gates){
  __shared__ float wt[8][KACT];
  int t = threadIdx.x; int j0 = blockIdx.x*8;
  for (int idx = t; idx < 8*KACT; idx += 256) {
    int r = idx / KACT, k = idx % KACT;
    int j = j0 + r;
    wt[r][k] = (k < E_) ? w_ih[j*E_ + k] : w_hh[j*H2_ + (k - E_)];
  }
  __syncthreads();
  int jq = t >> 7, b = t & 127;
  float acc[4] = {0.f,0.f,0.f,0.f};
  for (int k = 0; k < KACT; ++k) {
    float a = act[k*B_ + b];
    #pragma unroll
    for (int jj = 0; jj < 4; ++jj) acc[jj] += wt[jq*4+jj][k]*a;
  }
  #pragma unroll
  for (int jj = 0; jj < 4; ++jj) {
    int j = j0 + jq*4 + jj;
    gates[j*B_ + b] = acc[jj] + b_ih[j] + b_hh[j];
  }
}

// ---- K2: LSTM elementwise + hdot ----
__global__ __launch_bounds__(256) void k_lstm(const float* __restrict__ gates,
    const float* __restrict__ pre_c, const float* __restrict__ w_align,
    float* __restrict__ o_h, float* __restrict__ o_c,
    float* __restrict__ hc, float* __restrict__ hdot){
  __shared__ float red[256];
  int b = blockIdx.x, k = threadIdx.x;
  float i_ = gates[(0*H2_ + k)*B_ + b];
  float f_ = gates[(1*H2_ + k)*B_ + b];
  float g_ = gates[(2*H2_ + k)*B_ + b];
  float o_ = gates[(3*H2_ + k)*B_ + b];
  float c = sigmoidf_(f_)*pre_c[b*H2_ + k] + sigmoidf_(i_)*tanhf(g_);
  float h = sigmoidf_(o_)*tanhf(c);
  o_h[b*H2_ + k] = h;
  o_c[b*H2_ + k] = c;
  hc[k*B_ + b] = h;
  float s = blk_reduce_sum(h * w_align[H2_ + k], red);
  if (k == 0) hdot[b] = s;
}

// ---- K3a: scores, grid (8 chunks of 50, B) ----
__global__ __launch_bounds__(256) void k_scores(const float* __restrict__ enc,
    const float* __restrict__ cov, const float* __restrict__ w_align,
    const float* __restrict__ b_align, const float* __restrict__ hdot,
    const float* __restrict__ ab, float* __restrict__ sc){
  int b = blockIdx.y, c = blockIdx.x;
  int t = threadIdx.x, wave = t >> 6, lane = t & 63;
  float4 wa4 = *(const float4*)&w_align[lane*4];
  float hd = hdot[b], alpha = ab[0], beta = ab[1], ba = b_align[0];
  int t0 = c*50;
  for (int tt = t0 + wave; tt < t0 + 50; tt += 4) {
    const float4* ep = (const float4*)&enc[((size_t)b*T_ + tt)*H2_];
    float4 e4 = ep[lane];
    float d = e4.x*wa4.x + e4.y*wa4.y + e4.z*wa4.z + e4.w*wa4.w;
    #pragma unroll
    for (int m = 32; m >= 1; m >>= 1) d += __shfl_xor(d, m);
    if (lane == 0)
      sc[b*T_ + tt] = tanhf(d + hd + alpha*cov[b*T_ + tt] + beta + ba);
  }
}

// ---- K3b: softmax over T + scatter + newcov + covloss partial ----
__global__ __launch_bounds__(256) void k_soft(const float* __restrict__ sc_in,
    const float* __restrict__ cov, const int* __restrict__ src,
    float* __restrict__ o_attn, float* __restrict__ o_newcov,
    float* __restrict__ o_copy, float* __restrict__ covp,
    float* __restrict__ attn_ws){
  __shared__ float red[256];
  int b = blockIdx.x, t = threadIdx.x;
  float x1 = sc_in[b*T_ + t];
  float x2 = (t + 256 < T_) ? sc_in[b*T_ + t + 256] : -1e30f;
  float mx = blk_reduce_max(fmaxf(x1, x2), red);
  float e1 = __expf(x1 - mx);
  float e2 = (t + 256 < T_) ? __expf(x2 - mx) : 0.f;
  float sum = blk_reduce_sum(e1 + e2, red);
  float inv = 1.f/sum;
  float cl;
  {
    float a1 = e1*inv; float c1 = cov[b*T_ + t];
    attn_ws[b*T_ + t] = a1;
    o_attn[b*T_ + t] = a1;
    o_newcov[b*T_ + t] = c1 + a1;
    atomicAdd(&o_copy[(size_t)b*V_ + src[b*T_ + t]], a1);
    cl = fminf(a1, c1);
  }
  if (t + 256 < T_) {
    float a2 = e2*inv; float c2 = cov[b*T_ + t + 256];
    attn_ws[b*T_ + t + 256] = a2;
    o_attn[b*T_ + t + 256] = a2;
    o_newcov[b*T_ + t + 256] = c2 + a2;
    atomicAdd(&o_copy[(size_t)b*V_ + src[b*T_ + t + 256]], a2);
    cl += fminf(a2, c2);
  }
  float clsum = blk_reduce_sum(cl, red);
  if (t == 0) covp[b] = clsum;
}

// ---- K3c: context partials, grid (8 chunks, B) ----
__global__ __launch_bounds__(256) void k_ctx(const float* __restrict__ enc,
    const float* __restrict__ attn_ws, float* __restrict__ ctxp){
  __shared__ float a_s[50];
  int b = blockIdx.y, c = blockIdx.x, e = threadIdx.x;
  int t0 = c*50;
  if (e < 50) a_s[e] = attn_ws[b*T_ + t0 + e];
  __syncthreads();
  float acc = 0.f;
  #pragma unroll 5
  for (int i = 0; i < 50; ++i)
    acc += a_s[i] * enc[((size_t)b*T_ + t0 + i)*H2_ + e];
  ctxp[((size_t)b*8 + c)*H2_ + e] = acc;
}

// ---- K3d: context reduce + pgen ----
__global__ __launch_bounds__(256) void k_ctxpgen(const float* __restrict__ ctxp,
    const int* __restrict__ ids, const float* __restrict__ emb_table,
    const float* __restrict__ w_gen, const float* __restrict__ b_gen,
    float* __restrict__ hc, float* __restrict__ pgen){
  __shared__ float red[256];
  int b = blockIdx.x, t = threadIdx.x;
  float ctx = 0.f;
  #pragma unroll
  for (int c = 0; c < 8; ++c) ctx += ctxp[((size_t)b*8 + c)*H2_ + t];
  hc[(H2_ + t)*B_ + b] = ctx;
  float p = ctx*w_gen[t] + hc[t*B_ + b]*w_gen[H2_ + t];
  if (t < E_) p += emb_table[(size_t)ids[b]*E_ + t]*w_gen[2*H2_ + t];
  float s = blk_reduce_sum(p, red);
  if (t == 0) pgen[b] = sigmoidf_(s + b_gen[0]);
}

// ---- K4: fc1, output bf16 [b][k] ----
__global__ __launch_bounds__(256) void k_fc1(const float* __restrict__ hc,
    const float* __restrict__ w_fc1, const float* __restrict__ b_fc1,
    short* __restrict__ fcb){
  __shared__ float wt[16][H4_];
  int t = threadIdx.x; int j0 = blockIdx.x*16;
  for (int idx = t; idx < 16*H4_; idx += 256) {
    int r = idx >> 9, k = idx & 511;
    wt[r][k] = w_fc1[(j0 + r)*H4_ + k];
  }
  __syncthreads();
  int jq = t >> 7, b = t & 127;
  float acc[8] = {};
  for (int k = 0; k < H4_; ++k) {
    float a = hc[k*B_ + b];
    #pragma unroll
    for (int jj = 0; jj < 8; ++jj) acc[jj] += wt[jq*8+jj][k]*a;
  }
  bf16x8 pack;
  #pragma unroll
  for (int jj = 0; jj < 8; ++jj) {
    int j = j0 + jq*8 + jj;
    pack[jj] = f2bf(tanhf(acc[jj] + b_fc1[j]));
  }
  *(bf16x8*)&fcb[(size_t)b*H4_ + j0 + jq*8] = pack;
}

// ---- K5: MFMA bf16 GEMM, v-tile 32/block (2 waves), LDS-staged fcb chunks ----
// logits[b][v] = fcb[b][:]·w_fc2[v][:] + b_fc2[v]
#define KC 128
__global__ __launch_bounds__(128) void k_gemm2m(const short* __restrict__ fcb,
    const float* __restrict__ w_fc2, const float* __restrict__ b_fc2,
    float* __restrict__ logits){
  __shared__ short lds[B_*KC];          // 32 KB, XOR-swizzled [row][k]
  char* ldsb = (char*)lds;
  int t = threadIdx.x;
  int w = t >> 6, l = t & 63;
  int lo = l & 15, g = l >> 4;
  int v = blockIdx.x*32 + w*16 + lo;
  size_t vrow = (size_t)(v < V_ ? v : V_-1) * H4_;
  f32x4 acc[8] = {};
  for (int c = 0; c < 4; ++c) {
    int kc0 = c*KC;
    // stage fcb chunk [128 rows][128 k] bf16 into LDS (reg-staged, swizzled)
    #pragma unroll
    for (int qb = 0; qb < 4; ++qb) {
      bf16x8 s0, s1, s2, s3;
      {
        int lid = (qb*4 + 0)*128 + t; int row = lid >> 4, cg = lid & 15;
        s0 = *(const bf16x8*)&fcb[row*H4_ + kc0 + cg*8];
      }
      {
        int lid = (qb*4 + 1)*128 + t; int row = lid >> 4, cg = lid & 15;
        s1 = *(const bf16x8*)&fcb[row*H4_ + kc0 + cg*8];
      }
      {
        int lid = (qb*4 + 2)*128 + t; int row = lid >> 4, cg = lid & 15;
        s2 = *(const bf16x8*)&fcb[row*H4_ + kc0 + cg*8];
      }
      {
        int lid = (qb*4 + 3)*128 + t; int row = lid >> 4, cg = lid & 15;
        s3 = *(const bf16x8*)&fcb[row*H4_ + kc0 + cg*8];
      }
      {
        int lid = (qb*4 + 0)*128 + t; int row = lid >> 4, cg = lid & 15;
        *(bf16x8*)(ldsb + row*(KC*2) + ((cg*16) ^ ((row & 7) << 4))) = s0;
      }
      {
        int lid = (qb*4 + 1)*128 + t; int row = lid >> 4, cg = lid & 15;
        *(bf16x8*)(ldsb + row*(KC*2) + ((cg*16) ^ ((row & 7) << 4))) = s1;
      }
      {
        int lid = (qb*4 + 2)*128 + t; int row = lid >> 4, cg = lid & 15;
        *(bf16x8*)(ldsb + row*(KC*2) + ((cg*16) ^ ((row & 7) << 4))) = s2;
      }
      {
        int lid = (qb*4 + 3)*128 + t; int row = lid >> 4, cg = lid & 15;
        *(bf16x8*)(ldsb + row*(KC*2) + ((cg*16) ^ ((row & 7) << 4))) = s3;
      }
    }
    // issue full w prefetch queue for this chunk: 8 float4 (static regs)
    float4 wv[8];
    #pragma unroll
    for (int i = 0; i < 4; ++i) {
      wv[2*i]   = *(const float4*)&w_fc2[vrow + kc0 + i*32 + g*8];
      wv[2*i+1] = *(const float4*)&w_fc2[vrow + kc0 + i*32 + g*8 + 4];
    }
    __syncthreads();
    // consume: 4 k-steps of 32
    #pragma unroll
    for (int i = 0; i < 4; ++i) {
      bf16x8 bf;
      bf[0] = f2bf(wv[2*i].x);   bf[1] = f2bf(wv[2*i].y);
      bf[2] = f2bf(wv[2*i].z);   bf[3] = f2bf(wv[2*i].w);
      bf[4] = f2bf(wv[2*i+1].x); bf[5] = f2bf(wv[2*i+1].y);
      bf[6] = f2bf(wv[2*i+1].z); bf[7] = f2bf(wv[2*i+1].w);
      #pragma unroll
      for (int bg = 0; bg < 8; ++bg) {
        int row = bg*16 + lo;
        bf16x8 af = *(const bf16x8*)(ldsb + row*(KC*2) +
                       ((i*64 + g*16) ^ ((row & 7) << 4)));
        acc[bg] = __builtin_amdgcn_mfma_f32_16x16x32_bf16(af, bf, acc[bg], 0, 0, 0);
      }
    }
    __syncthreads();
  }
  if (v < V_) {
    float bias = b_fc2[v];
    #pragma unroll
    for (int bg = 0; bg < 8; ++bg) {
      #pragma unroll
      for (int r = 0; r < 4; ++r) {
        int b = bg*16 + g*4 + r;
        logits[(size_t)b*V_ + v] = acc[bg][r] + bias;
      }
    }
  }
}

// ---- K6a: softmax partial stats, grid (8, B) ----
__global__ __launch_bounds__(256) void k_smp(const float* __restrict__ logits,
    float* __restrict__ smp){
  __shared__ float rm[256], rs[256];
  int b = blockIdx.y, c = blockIdx.x, t = threadIdx.x;
  int v0 = c*6250, v1 = v0 + 6250;
  float m = -1e30f, s = 0.f;
  for (int v = v0 + t; v < v1; v += 256) {
    float x = logits[(size_t)b*V_ + v];
    float nm = fmaxf(m, x);
    s = s*__expf(m - nm) + __expf(x - nm);
    m = nm;
  }
  rm[t] = m; rs[t] = s; __syncthreads();
  for (int k = 128; k > 0; k >>= 1) {
    if (t < k) {
      float m1 = rm[t], s1 = rs[t], m2 = rm[t+k], s2 = rs[t+k];
      float nm = fmaxf(m1, m2);
      rm[t] = nm; rs[t] = s1*__expf(m1-nm) + s2*__expf(m2-nm);
    }
    __syncthreads();
  }
  if (t == 0) { smp[(b*8+c)*2] = rm[0]; smp[(b*8+c)*2+1] = rs[0]; }
}

// ---- K6b: combine stats + covloss ----
__global__ __launch_bounds__(128) void k_smred_cl(const float* __restrict__ smp,
    const float* __restrict__ covp, float* __restrict__ mx,
    float* __restrict__ inv, float* __restrict__ o_cl){
  __shared__ float red[128];
  int t = threadIdx.x;
  float m = -1e30f, s = 0.f;
  #pragma unroll
  for (int c = 0; c < 8; ++c) {
    float m2 = smp[(t*8+c)*2], s2 = smp[(t*8+c)*2+1];
    float nm = fmaxf(m, m2);
    s = s*__expf(m - nm) + s2*__expf(m2 - nm);
    m = nm;
  }
  mx[t] = m; inv[t] = 1.f/s;
  red[t] = covp[t]; __syncthreads();
  for (int k = 64; k > 0; k >>= 1){ if (t < k) red[t] += red[t+k]; __syncthreads(); }
  if (t == 0) o_cl[0] = red[0];
}

// ---- K7: final mix (float4) ----
__global__ __launch_bounds__(256) void k_final(const float* __restrict__ copy,
    const float* __restrict__ mx, const float* __restrict__ inv_s,
    const float* __restrict__ pgen, float* __restrict__ out){
  size_t gid = (size_t)blockIdx.x*256 + threadIdx.x;
  int b = (int)(gid / (V_/4));
  int v = (int)(gid % (V_/4))*4;
  size_t idx = (size_t)b*V_ + v;
  float m = mx[b], is = inv_s[b], pg = pgen[b];
  float4 lg = *(const float4*)&out[idx];
  float4 cp = *(const float4*)&copy[idx];
  float4 o;
  o.x = __expf(lg.x - m)*is*pg + cp.x*(1.f - pg);
  o.y = __expf(lg.y - m)*is*pg + cp.y*(1.f - pg);
  o.z = __expf(lg.z - m)*is*pg + cp.z*(1.f - pg);
  o.w = __expf(lg.w - m)*is*pg + cp.w*(1.f - pg);
  *(float4*)&out[idx] = o;
}

extern "C" void kernel_launch(void* const* d_in, const int* in_sizes, int n_in,
                              void* d_out, int out_size, void* d_ws, size_t ws_size,
                              hipStream_t stream) {
  const int*   ids       = (const int*)  d_in[0];
  const float* pre_h     = (const float*)d_in[1];
  const float* pre_c     = (const float*)d_in[2];
  const float* enc       = (const float*)d_in[3];
  const int*   src       = (const int*)  d_in[4];
  const float* cov       = (const float*)d_in[5];
  const float* emb_table = (const float*)d_in[6];
  const float* w_ih      = (const float*)d_in[7];
  const float* w_hh      = (const float*)d_in[8];
  const float* b_ih      = (const float*)d_in[9];
  const float* b_hh      = (const float*)d_in[10];
  const float* w_align   = (const float*)d_in[11];
  const float* b_align   = (const float*)d_in[12];
  const float* w_cov     = (const float*)d_in[13];
  const float* b_cov     = (const float*)d_in[14];
  const float* w_fc1     = (const float*)d_in[15];
  const float* b_fc1     = (const float*)d_in[16];
  const float* w_fc2     = (const float*)d_in[17];
  const float* b_fc2     = (const float*)d_in[18];
  const float* w_gen     = (const float*)d_in[19];
  const float* b_gen     = (const float*)d_in[20];

  float* out = (float*)d_out;
  float* ws  = (float*)d_ws;

  float* o_out    = out;
  float* o_h      = out + OFF_H;
  float* o_c      = out + OFF_C;
  float* o_attn   = out + OFF_ATTN;
  float* o_copy   = out + OFF_COPY;
  float* o_newcov = out + OFF_NEWCOV;
  float* o_cl     = out + OFF_COVLOSS;

  hipMemsetAsync(o_copy, 0, (size_t)B_*V_*sizeof(float), stream);

  k_act  <<<192, 256, 0, stream>>>(ids, pre_h, emb_table, w_align, w_cov, b_cov,
                                   ws + WS_ACT, ws + WS_AB);
  k_gates<<<128, 256, 0, stream>>>(ws + WS_ACT, w_ih, w_hh, b_ih, b_hh, ws + WS_GATES);
  k_lstm <<<128, 256, 0, stream>>>(ws + WS_GATES, pre_c, w_align, o_h, o_c,
                                   ws + WS_HC, ws + WS_HDOT);
  k_scores<<<dim3(8,128), 256, 0, stream>>>(enc, cov, w_align, b_align,
                                   ws + WS_HDOT, ws + WS_AB, ws + WS_SC);
  k_soft <<<128, 256, 0, stream>>>(ws + WS_SC, cov, src, o_attn, o_newcov, o_copy,
                                   ws + WS_COVP, ws + WS_ATTN);
  k_ctx  <<<dim3(8,128), 256, 0, stream>>>(enc, ws + WS_ATTN, ws + WS_CTXP);
  k_ctxpgen<<<128, 256, 0, stream>>>(ws + WS_CTXP, ids, emb_table, w_gen, b_gen,
                                   ws + WS_HC, ws + WS_PGEN);
  k_fc1  <<<32, 256, 0, stream>>>(ws + WS_HC, w_fc1, b_fc1, (short*)(ws + WS_FCB));
  k_gemm2m<<<(V_ + 31)/32, 128, 0, stream>>>((const short*)(ws + WS_FCB),
                                   w_fc2, b_fc2, o_out);
  k_smp  <<<dim3(8,128), 256, 0, stream>>>(o_out, ws + WS_SMP);
  k_smred_cl<<<1, 128, 0, stream>>>(ws + WS_SMP, ws + WS_COVP,
                                   ws + WS_MAX, ws + WS_INV, o_cl);
  k_final<<<(int)(((size_t)B_*V_/4)/256), 256, 0, stream>>>(
      o_copy, ws + WS_MAX, ws + WS_INV, ws + WS_PGEN, o_out);
}

// Round 4
// 149.795 us; speedup vs baseline: 2.4574x; 1.0301x over previous
//
#include <hip/hip_runtime.h>
#include <hip/hip_bf16.h>
#include <math.h>

#define B_  128
#define T_  400
#define E_  128
#define H2_ 256
#define H4_ 512
#define V_  50000
#define G4_ 1024   // 4*H2
#define KACT 384   // E + H2

// output offsets (floats)
#define OFF_H       6400000
#define OFF_C       6432768
#define OFF_ATTN    6465536
#define OFF_COPY    6516736
#define OFF_NEWCOV 12916736
#define OFF_COVLOSS 12967936

// workspace offsets (floats)
#define WS_ACT   0                      // [384][128] act (emb;h0) [k][b]
#define WS_GATES (WS_ACT + KACT*B_)     // [1024][128] gates [j][b]
#define WS_HC    (WS_GATES + G4_*B_)    // [512][128]  (h;ctx) [k][b]
#define WS_FCB   (WS_HC + H4_*B_)       // [128][512]  fc bf16 [b][k] (32768 floats)
#define WS_SC    (WS_FCB + H4_*B_/2)    // [128][400]  scores
#define WS_ATTN  (WS_SC + B_*T_)        // [128][400]  attn
#define WS_CTXP  (WS_ATTN + B_*T_)      // [128][8][256] context partials
#define WS_SMP   (WS_CTXP + B_*8*H2_)   // [128][8][2] softmax partials
#define WS_HDOT  (WS_SMP + B_*8*2)      // [128]
#define WS_COVP  (WS_HDOT + B_)         // [128]
#define WS_PGEN  (WS_COVP + B_)         // [128]
#define WS_MAX   (WS_PGEN + B_)         // [128]
#define WS_INV   (WS_MAX + B_)          // [128]
#define WS_AB    (WS_INV + B_)          // [2] alpha, beta

typedef __attribute__((ext_vector_type(8))) short bf16x8;
typedef __attribute__((ext_vector_type(4))) float f32x4;
typedef __attribute__((ext_vector_type(16))) float f32x16;

__device__ inline float sigmoidf_(float x){ return 1.f/(1.f+__expf(-x)); }

__device__ inline short f2bf(float x){
  __hip_bfloat16 h = __float2bfloat16(x);
  return *reinterpret_cast<short*>(&h);
}

__device__ inline float blk_reduce_sum(float v, float* red){
  int t = threadIdx.x;
  red[t] = v; __syncthreads();
  for (int s = 128; s > 0; s >>= 1){ if (t < s) red[t] += red[t+s]; __syncthreads(); }
  float r = red[0]; __syncthreads(); return r;
}
__device__ inline float blk_reduce_max(float v, float* red){
  int t = threadIdx.x;
  red[t] = v; __syncthreads();
  for (int s = 128; s > 0; s >>= 1){ if (t < s) red[t] = fmaxf(red[t], red[t+s]); __syncthreads(); }
  float r = red[0]; __syncthreads(); return r;
}

// ---- K0: act[k][b] = concat(emb,h0) transposed; block 0 also computes alpha/beta ----
__global__ __launch_bounds__(256) void k_act(const int* __restrict__ ids,
    const float* __restrict__ pre_h, const float* __restrict__ emb_table,
    const float* __restrict__ w_align, const float* __restrict__ w_cov,
    const float* __restrict__ b_cov, float* __restrict__ act,
    float* __restrict__ ab){
  __shared__ float red[256];
  int t = threadIdx.x;
  int idx = blockIdx.x*256 + t;
  int k = idx >> 7, b = idx & 127;
  float v = (k < E_) ? emb_table[(size_t)ids[b]*E_ + k]
                     : pre_h[b*H2_ + (k - E_)];
  act[idx] = v;
  if (blockIdx.x == 0) {
    float wa = w_align[2*H2_ + t];
    float alpha = blk_reduce_sum(w_cov[t]*wa, red);
    float beta  = blk_reduce_sum(b_cov[t]*wa, red);
    if (t == 0) { ab[0] = alpha; ab[1] = beta; }
  }
}

// ---- K1: gates[j][b] ----
__global__ __launch_bounds__(256) void k_gates(const float* __restrict__ act,
    const float* __restrict__ w_ih, const float* __restrict__ w_hh,
    const float* __restrict__ b_ih, const float* __restrict__ b_hh,
    float* __restrict__ gates){
  __shared__ float wt[8][KACT];
  int t = threadIdx.x; int j0 = blockIdx.x*8;
  for (int idx = t; idx < 8*KACT; idx += 256) {
    int r = idx / KACT, k = idx % KACT;
    int j = j0 + r;
    wt[r][k] = (k < E_) ? w_ih[j*E_ + k] : w_hh[j*H2_ + (k - E_)];
  }
  __syncthreads();
  int jq = t >> 7, b = t & 127;
  float acc[4] = {0.f,0.f,0.f,0.f};
  for (int k = 0; k < KACT; ++k) {
    float a = act[k*B_ + b];
    #pragma unroll
    for (int jj = 0; jj < 4; ++jj) acc[jj] += wt[jq*4+jj][k]*a;
  }
  #pragma unroll
  for (int jj = 0; jj < 4; ++jj) {
    int j = j0 + jq*4 + jj;
    gates[j*B_ + b] = acc[jj] + b_ih[j] + b_hh[j];
  }
}

// ---- K2: LSTM elementwise + hdot ----
__global__ __launch_bounds__(256) void k_lstm(const float* __restrict__ gates,
    const float* __restrict__ pre_c, const float* __restrict__ w_align,
    float* __restrict__ o_h, float* __restrict__ o_c,
    float* __restrict__ hc, float* __restrict__ hdot){
  __shared__ float red[256];
  int b = blockIdx.x, k = threadIdx.x;
  float i_ = gates[(0*H2_ + k)*B_ + b];
  float f_ = gates[(1*H2_ + k)*B_ + b];
  float g_ = gates[(2*H2_ + k)*B_ + b];
  float o_ = gates[(3*H2_ + k)*B_ + b];
  float c = sigmoidf_(f_)*pre_c[b*H2_ + k] + sigmoidf_(i_)*tanhf(g_);
  float h = sigmoidf_(o_)*tanhf(c);
  o_h[b*H2_ + k] = h;
  o_c[b*H2_ + k] = c;
  hc[k*B_ + b] = h;
  float s = blk_reduce_sum(h * w_align[H2_ + k], red);
  if (k == 0) hdot[b] = s;
}

// ---- K3a: scores, grid (8 chunks of 50, B) ----
__global__ __launch_bounds__(256) void k_scores(const float* __restrict__ enc,
    const float* __restrict__ cov, const float* __restrict__ w_align,
    const float* __restrict__ b_align, const float* __restrict__ hdot,
    const float* __restrict__ ab, float* __restrict__ sc){
  int b = blockIdx.y, c = blockIdx.x;
  int t = threadIdx.x, wave = t >> 6, lane = t & 63;
  float4 wa4 = *(const float4*)&w_align[lane*4];
  float hd = hdot[b], alpha = ab[0], beta = ab[1], ba = b_align[0];
  int t0 = c*50;
  for (int tt = t0 + wave; tt < t0 + 50; tt += 4) {
    const float4* ep = (const float4*)&enc[((size_t)b*T_ + tt)*H2_];
    float4 e4 = ep[lane];
    float d = e4.x*wa4.x + e4.y*wa4.y + e4.z*wa4.z + e4.w*wa4.w;
    #pragma unroll
    for (int m = 32; m >= 1; m >>= 1) d += __shfl_xor(d, m);
    if (lane == 0)
      sc[b*T_ + tt] = tanhf(d + hd + alpha*cov[b*T_ + tt] + beta + ba);
  }
}

// ---- K3b: softmax over T + scatter + newcov + covloss partial ----
__global__ __launch_bounds__(256) void k_soft(const float* __restrict__ sc_in,
    const float* __restrict__ cov, const int* __restrict__ src,
    float* __restrict__ o_attn, float* __restrict__ o_newcov,
    float* __restrict__ o_copy, float* __restrict__ covp,
    float* __restrict__ attn_ws){
  __shared__ float red[256];
  int b = blockIdx.x, t = threadIdx.x;
  float x1 = sc_in[b*T_ + t];
  float x2 = (t + 256 < T_) ? sc_in[b*T_ + t + 256] : -1e30f;
  float mx = blk_reduce_max(fmaxf(x1, x2), red);
  float e1 = __expf(x1 - mx);
  float e2 = (t + 256 < T_) ? __expf(x2 - mx) : 0.f;
  float sum = blk_reduce_sum(e1 + e2, red);
  float inv = 1.f/sum;
  float cl;
  {
    float a1 = e1*inv; float c1 = cov[b*T_ + t];
    attn_ws[b*T_ + t] = a1;
    o_attn[b*T_ + t] = a1;
    o_newcov[b*T_ + t] = c1 + a1;
    atomicAdd(&o_copy[(size_t)b*V_ + src[b*T_ + t]], a1);
    cl = fminf(a1, c1);
  }
  if (t + 256 < T_) {
    float a2 = e2*inv; float c2 = cov[b*T_ + t + 256];
    attn_ws[b*T_ + t + 256] = a2;
    o_attn[b*T_ + t + 256] = a2;
    o_newcov[b*T_ + t + 256] = c2 + a2;
    atomicAdd(&o_copy[(size_t)b*V_ + src[b*T_ + t + 256]], a2);
    cl += fminf(a2, c2);
  }
  float clsum = blk_reduce_sum(cl, red);
  if (t == 0) covp[b] = clsum;
}

// ---- K3c: context partials, grid (8 chunks, B) ----
__global__ __launch_bounds__(256) void k_ctx(const float* __restrict__ enc,
    const float* __restrict__ attn_ws, float* __restrict__ ctxp){
  __shared__ float a_s[50];
  int b = blockIdx.y, c = blockIdx.x, e = threadIdx.x;
  int t0 = c*50;
  if (e < 50) a_s[e] = attn_ws[b*T_ + t0 + e];
  __syncthreads();
  float acc = 0.f;
  #pragma unroll 5
  for (int i = 0; i < 50; ++i)
    acc += a_s[i] * enc[((size_t)b*T_ + t0 + i)*H2_ + e];
  ctxp[((size_t)b*8 + c)*H2_ + e] = acc;
}

// ---- K3d: context reduce + pgen ----
__global__ __launch_bounds__(256) void k_ctxpgen(const float* __restrict__ ctxp,
    const int* __restrict__ ids, const float* __restrict__ emb_table,
    const float* __restrict__ w_gen, const float* __restrict__ b_gen,
    float* __restrict__ hc, float* __restrict__ pgen){
  __shared__ float red[256];
  int b = blockIdx.x, t = threadIdx.x;
  float ctx = 0.f;
  #pragma unroll
  for (int c = 0; c < 8; ++c) ctx += ctxp[((size_t)b*8 + c)*H2_ + t];
  hc[(H2_ + t)*B_ + b] = ctx;
  float p = ctx*w_gen[t] + hc[t*B_ + b]*w_gen[H2_ + t];
  if (t < E_) p += emb_table[(size_t)ids[b]*E_ + t]*w_gen[2*H2_ + t];
  float s = blk_reduce_sum(p, red);
  if (t == 0) pgen[b] = sigmoidf_(s + b_gen[0]);
}

// ---- K4: fc1, output bf16 [b][k] ----
__global__ __launch_bounds__(256) void k_fc1(const float* __restrict__ hc,
    const float* __restrict__ w_fc1, const float* __restrict__ b_fc1,
    short* __restrict__ fcb){
  __shared__ float wt[16][H4_];
  int t = threadIdx.x; int j0 = blockIdx.x*16;
  for (int idx = t; idx < 16*H4_; idx += 256) {
    int r = idx >> 9, k = idx & 511;
    wt[r][k] = w_fc1[(j0 + r)*H4_ + k];
  }
  __syncthreads();
  int jq = t >> 7, b = t & 127;
  float acc[8] = {};
  for (int k = 0; k < H4_; ++k) {
    float a = hc[k*B_ + b];
    #pragma unroll
    for (int jj = 0; jj < 8; ++jj) acc[jj] += wt[jq*8+jj][k]*a;
  }
  bf16x8 pack;
  #pragma unroll
  for (int jj = 0; jj < 8; ++jj) {
    int j = j0 + jq*8 + jj;
    pack[jj] = f2bf(tanhf(acc[jj] + b_fc1[j]));
  }
  *(bf16x8*)&fcb[(size_t)b*H4_ + j0 + jq*8] = pack;
}

// ---- K5: MFMA 32x32x16 GEMM. logits[b][v] = fcb[b][:]·w_fc2[v][:] + b_fc2[v]
// 256 thr (4 waves), v-tile 128 (32 v/wave), fcb staged in 2 half-K LDS slabs.
#define KH 256
__global__ __launch_bounds__(256, 2) void k_gemm2m(const short* __restrict__ fcb,
    const float* __restrict__ w_fc2, const float* __restrict__ b_fc2,
    float* __restrict__ logits){
  __shared__ short lds[B_*KH];          // 64 KB, rows 512B, XOR-swizzled
  char* ldsb = (char*)lds;
  int t = threadIdx.x;
  int w = t >> 6, l = t & 63;
  int ln = l & 31, g2 = l >> 5;
  int v = blockIdx.x*128 + w*32 + ln;
  int vc = v < V_ ? v : V_ - 1;
  f32x16 acc0 = {}, acc1 = {}, acc2 = {}, acc3 = {};

  #pragma unroll
  for (int h = 0; h < 2; ++h) {
    int kb = h*KH;
    if (h) __syncthreads();             // all waves done reading slab 0
    // stage fcb[:, kb..kb+255] -> LDS (reg-staged, swizzled)
    #pragma unroll
    for (int r = 0; r < 16; ++r) {
      int lid = r*256 + t;
      int row = lid >> 5, cg = lid & 31;
      bf16x8 d = *(const bf16x8*)&fcb[row*H4_ + kb + cg*8];
      *(bf16x8*)(ldsb + row*512 + ((cg*16) ^ ((row & 7) << 4))) = d;
    }
    __syncthreads();

    const float* wrow = w_fc2 + (size_t)vc*H4_ + kb + g2*8;
    float4 a0,b0,a1,b1,a2,b2,a3,b3;
    #define LW(s, i) { a##s = *(const float4*)(wrow + (i)*16); \
                       b##s = *(const float4*)(wrow + (i)*16 + 4); }
    #define STEP(s, i)                                                        \
    {                                                                         \
      bf16x8 bf;                                                              \
      bf[0]=f2bf(a##s.x); bf[1]=f2bf(a##s.y); bf[2]=f2bf(a##s.z);             \
      bf[3]=f2bf(a##s.w); bf[4]=f2bf(b##s.x); bf[5]=f2bf(b##s.y);             \
      bf[6]=f2bf(b##s.z); bf[7]=f2bf(b##s.w);                                 \
      int kbyte = (i)*32 + g2*16;                                             \
      { int row = ln;                                                         \
        bf16x8 af = *(const bf16x8*)(ldsb + row*512 + (kbyte ^ ((row&7)<<4)));\
        acc0 = __builtin_amdgcn_mfma_f32_32x32x16_bf16(af, bf, acc0, 0,0,0); }\
      { int row = 32 + ln;                                                    \
        bf16x8 af = *(const bf16x8*)(ldsb + row*512 + (kbyte ^ ((row&7)<<4)));\
        acc1 = __builtin_amdgcn_mfma_f32_32x32x16_bf16(af, bf, acc1, 0,0,0); }\
      { int row = 64 + ln;                                                    \
        bf16x8 af = *(const bf16x8*)(ldsb + row*512 + (kbyte ^ ((row&7)<<4)));\
        acc2 = __builtin_amdgcn_mfma_f32_32x32x16_bf16(af, bf, acc2, 0,0,0); }\
      { int row = 96 + ln;                                                    \
        bf16x8 af = *(const bf16x8*)(ldsb + row*512 + (kbyte ^ ((row&7)<<4)));\
        acc3 = __builtin_amdgcn_mfma_f32_32x32x16_bf16(af, bf, acc3, 0,0,0); }\
    }
    LW(0,0) LW(1,1) LW(2,2) LW(3,3)
    STEP(0,0)  LW(0,4)
    STEP(1,1)  LW(1,5)
    STEP(2,2)  LW(2,6)
    STEP(3,3)  LW(3,7)
    STEP(0,4)  LW(0,8)
    STEP(1,5)  LW(1,9)
    STEP(2,6)  LW(2,10)
    STEP(3,7)  LW(3,11)
    STEP(0,8)  LW(0,12)
    STEP(1,9)  LW(1,13)
    STEP(2,10) LW(2,14)
    STEP(3,11) LW(3,15)
    STEP(0,12)
    STEP(1,13)
    STEP(2,14)
    STEP(3,15)
    #undef LW
    #undef STEP
  }

  if (v < V_) {
    float bias = b_fc2[v];
    #pragma unroll
    for (int r = 0; r < 16; ++r) {
      int brow = (r & 3) + 8*(r >> 2) + 4*g2;
      logits[(size_t)(brow)*V_ + v]      = acc0[r] + bias;
      logits[(size_t)(32 + brow)*V_ + v] = acc1[r] + bias;
      logits[(size_t)(64 + brow)*V_ + v] = acc2[r] + bias;
      logits[(size_t)(96 + brow)*V_ + v] = acc3[r] + bias;
    }
  }
}

// ---- K6a: softmax partial stats, grid (8, B) ----
__global__ __launch_bounds__(256) void k_smp(const float* __restrict__ logits,
    float* __restrict__ smp){
  __shared__ float rm[256], rs[256];
  int b = blockIdx.y, c = blockIdx.x, t = threadIdx.x;
  int v0 = c*6250, v1 = v0 + 6250;
  float m = -1e30f, s = 0.f;
  for (int v = v0 + t; v < v1; v += 256) {
    float x = logits[(size_t)b*V_ + v];
    float nm = fmaxf(m, x);
    s = s*__expf(m - nm) + __expf(x - nm);
    m = nm;
  }
  rm[t] = m; rs[t] = s; __syncthreads();
  for (int k = 128; k > 0; k >>= 1) {
    if (t < k) {
      float m1 = rm[t], s1 = rs[t], m2 = rm[t+k], s2 = rs[t+k];
      float nm = fmaxf(m1, m2);
      rm[t] = nm; rs[t] = s1*__expf(m1-nm) + s2*__expf(m2-nm);
    }
    __syncthreads();
  }
  if (t == 0) { smp[(b*8+c)*2] = rm[0]; smp[(b*8+c)*2+1] = rs[0]; }
}

// ---- K6b: combine stats + covloss ----
__global__ __launch_bounds__(128) void k_smred_cl(const float* __restrict__ smp,
    const float* __restrict__ covp, float* __restrict__ mx,
    float* __restrict__ inv, float* __restrict__ o_cl){
  __shared__ float red[128];
  int t = threadIdx.x;
  float m = -1e30f, s = 0.f;
  #pragma unroll
  for (int c = 0; c < 8; ++c) {
    float m2 = smp[(t*8+c)*2], s2 = smp[(t*8+c)*2+1];
    float nm = fmaxf(m, m2);
    s = s*__expf(m - nm) + s2*__expf(m2 - nm);
    m = nm;
  }
  mx[t] = m; inv[t] = 1.f/s;
  red[t] = covp[t]; __syncthreads();
  for (int k = 64; k > 0; k >>= 1){ if (t < k) red[t] += red[t+k]; __syncthreads(); }
  if (t == 0) o_cl[0] = red[0];
}

// ---- K7: final mix (float4) ----
__global__ __launch_bounds__(256) void k_final(const float* __restrict__ copy,
    const float* __restrict__ mx, const float* __restrict__ inv_s,
    const float* __restrict__ pgen, float* __restrict__ out){
  size_t gid = (size_t)blockIdx.x*256 + threadIdx.x;
  int b = (int)(gid / (V_/4));
  int v = (int)(gid % (V_/4))*4;
  size_t idx = (size_t)b*V_ + v;
  float m = mx[b], is = inv_s[b], pg = pgen[b];
  float4 lg = *(const float4*)&out[idx];
  float4 cp = *(const float4*)&copy[idx];
  float4 o;
  o.x = __expf(lg.x - m)*is*pg + cp.x*(1.f - pg);
  o.y = __expf(lg.y - m)*is*pg + cp.y*(1.f - pg);
  o.z = __expf(lg.z - m)*is*pg + cp.z*(1.f - pg);
  o.w = __expf(lg.w - m)*is*pg + cp.w*(1.f - pg);
  *(float4*)&out[idx] = o;
}

extern "C" void kernel_launch(void* const* d_in, const int* in_sizes, int n_in,
                              void* d_out, int out_size, void* d_ws, size_t ws_size,
                              hipStream_t stream) {
  const int*   ids       = (const int*)  d_in[0];
  const float* pre_h     = (const float*)d_in[1];
  const float* pre_c     = (const float*)d_in[2];
  const float* enc       = (const float*)d_in[3];
  const int*   src       = (const int*)  d_in[4];
  const float* cov       = (const float*)d_in[5];
  const float* emb_table = (const float*)d_in[6];
  const float* w_ih      = (const float*)d_in[7];
  const float* w_hh      = (const float*)d_in[8];
  const float* b_ih      = (const float*)d_in[9];
  const float* b_hh      = (const float*)d_in[10];
  const float* w_align   = (const float*)d_in[11];
  const float* b_align   = (const float*)d_in[12];
  const float* w_cov     = (const float*)d_in[13];
  const float* b_cov     = (const float*)d_in[14];
  const float* w_fc1     = (const float*)d_in[15];
  const float* b_fc1     = (const float*)d_in[16];
  const float* w_fc2     = (const float*)d_in[17];
  const float* b_fc2     = (const float*)d_in[18];
  const float* w_gen     = (const float*)d_in[19];
  const float* b_gen     = (const float*)d_in[20];

  float* out = (float*)d_out;
  float* ws  = (float*)d_ws;

  float* o_out    = out;
  float* o_h      = out + OFF_H;
  float* o_c      = out + OFF_C;
  float* o_attn   = out + OFF_ATTN;
  float* o_copy   = out + OFF_COPY;
  float* o_newcov = out + OFF_NEWCOV;
  float* o_cl     = out + OFF_COVLOSS;

  hipMemsetAsync(o_copy, 0, (size_t)B_*V_*sizeof(float), stream);

  k_act  <<<192, 256, 0, stream>>>(ids, pre_h, emb_table, w_align, w_cov, b_cov,
                                   ws + WS_ACT, ws + WS_AB);
  k_gates<<<128, 256, 0, stream>>>(ws + WS_ACT, w_ih, w_hh, b_ih, b_hh, ws + WS_GATES);
  k_lstm <<<128, 256, 0, stream>>>(ws + WS_GATES, pre_c, w_align, o_h, o_c,
                                   ws + WS_HC, ws + WS_HDOT);
  k_scores<<<dim3(8,128), 256, 0, stream>>>(enc, cov, w_align, b_align,
                                   ws + WS_HDOT, ws + WS_AB, ws + WS_SC);
  k_soft <<<128, 256, 0, stream>>>(ws + WS_SC, cov, src, o_attn, o_newcov, o_copy,
                                   ws + WS_COVP, ws + WS_ATTN);
  k_ctx  <<<dim3(8,128), 256, 0, stream>>>(enc, ws + WS_ATTN, ws + WS_CTXP);
  k_ctxpgen<<<128, 256, 0, stream>>>(ws + WS_CTXP, ids, emb_table, w_gen, b_gen,
                                   ws + WS_HC, ws + WS_PGEN);
  k_fc1  <<<32, 256, 0, stream>>>(ws + WS_HC, w_fc1, b_fc1, (short*)(ws + WS_FCB));
  k_gemm2m<<<(V_ + 127)/128, 256, 0, stream>>>((const short*)(ws + WS_FCB),
                                   w_fc2, b_fc2, o_out);
  k_smp  <<<dim3(8,128), 256, 0, stream>>>(o_out, ws + WS_SMP);
  k_smred_cl<<<1, 128, 0, stream>>>(ws + WS_SMP, ws + WS_COVP,
                                   ws + WS_MAX, ws + WS_INV, o_cl);
  k_final<<<(int)(((size_t)B_*V_/4)/256), 256, 0, stream>>>(
      o_copy, ws + WS_MAX, ws + WS_INV, ws + WS_PGEN, o_out);
}

// Round 5
// 149.677 us; speedup vs baseline: 2.4593x; 1.0008x over previous
//
#include <hip/hip_runtime.h>
#include <hip/hip_bf16.h>
#include <math.h>

#define B_  128
#define T_  400
#define E_  128
#define H2_ 256
#define H4_ 512
#define V_  50000
#define G4_ 1024   // 4*H2
#define KACT 384   // E + H2

// output offsets (floats)
#define OFF_H       6400000
#define OFF_C       6432768
#define OFF_ATTN    6465536
#define OFF_COPY    6516736
#define OFF_NEWCOV 12916736
#define OFF_COVLOSS 12967936

// workspace offsets (floats)
#define WS_ACT   0                      // [384][128] act (emb;h0) [k][b]
#define WS_GATES (WS_ACT + KACT*B_)     // [1024][128] gates [j][b]
#define WS_HC    (WS_GATES + G4_*B_)    // [512][128]  (h;ctx) [k][b]
#define WS_FCB   (WS_HC + H4_*B_)       // [128][512]  fc bf16 [b][k] (32768 floats)
#define WS_SC    (WS_FCB + H4_*B_/2)    // [128][400]  scores
#define WS_ATTN  (WS_SC + B_*T_)        // [128][400]  attn
#define WS_CTXP  (WS_ATTN + B_*T_)      // [128][8][256] context partials
#define WS_SMP   (WS_CTXP + B_*8*H2_)   // [128][8][2] softmax partials
#define WS_HDOT  (WS_SMP + B_*8*2)      // [128]
#define WS_COVP  (WS_HDOT + B_)         // [128]
#define WS_PGEN  (WS_COVP + B_)         // [128]
#define WS_MAX   (WS_PGEN + B_)         // [128]
#define WS_INV   (WS_MAX + B_)          // [128]
#define WS_AB    (WS_INV + B_)          // [2] alpha, beta

typedef __attribute__((ext_vector_type(8))) short bf16x8;
typedef __attribute__((ext_vector_type(4))) float f32x4;
typedef __attribute__((ext_vector_type(16))) float f32x16;

__device__ inline float sigmoidf_(float x){ return 1.f/(1.f+__expf(-x)); }

__device__ inline short f2bf(float x){
  __hip_bfloat16 h = __float2bfloat16(x);
  return *reinterpret_cast<short*>(&h);
}

__device__ inline float blk_reduce_sum(float v, float* red){
  int t = threadIdx.x;
  red[t] = v; __syncthreads();
  for (int s = 128; s > 0; s >>= 1){ if (t < s) red[t] += red[t+s]; __syncthreads(); }
  float r = red[0]; __syncthreads(); return r;
}
__device__ inline float blk_reduce_max(float v, float* red){
  int t = threadIdx.x;
  red[t] = v; __syncthreads();
  for (int s = 128; s > 0; s >>= 1){ if (t < s) red[t] = fmaxf(red[t], red[t+s]); __syncthreads(); }
  float r = red[0]; __syncthreads(); return r;
}

// ---- K_zero: fast zero of o_copy (float4, saturating grid) ----
__global__ __launch_bounds__(256) void k_zero(float* __restrict__ p){
  size_t i = ((size_t)blockIdx.x*256 + threadIdx.x)*4;
  if (i < (size_t)B_*V_)
    *(float4*)&p[i] = make_float4(0.f,0.f,0.f,0.f);
}

// ---- K0: act[k][b] = concat(emb,h0) transposed; block 0 also computes alpha/beta ----
__global__ __launch_bounds__(256) void k_act(const int* __restrict__ ids,
    const float* __restrict__ pre_h, const float* __restrict__ emb_table,
    const float* __restrict__ w_align, const float* __restrict__ w_cov,
    const float* __restrict__ b_cov, float* __restrict__ act,
    float* __restrict__ ab){
  __shared__ float red[256];
  int t = threadIdx.x;
  int idx = blockIdx.x*256 + t;
  int k = idx >> 7, b = idx & 127;
  float v = (k < E_) ? emb_table[(size_t)ids[b]*E_ + k]
                     : pre_h[b*H2_ + (k - E_)];
  act[idx] = v;
  if (blockIdx.x == 0) {
    float wa = w_align[2*H2_ + t];
    float alpha = blk_reduce_sum(w_cov[t]*wa, red);
    float beta  = blk_reduce_sum(b_cov[t]*wa, red);
    if (t == 0) { ab[0] = alpha; ab[1] = beta; }
  }
}

// ---- K1: gates[j][b] ----
__global__ __launch_bounds__(256) void k_gates(const float* __restrict__ act,
    const float* __restrict__ w_ih, const float* __restrict__ w_hh,
    const float* __restrict__ b_ih, const float* __restrict__ b_hh,
    float* __restrict__ gates){
  __shared__ float wt[8][KACT];
  int t = threadIdx.x; int j0 = blockIdx.x*8;
  for (int idx = t; idx < 8*KACT; idx += 256) {
    int r = idx / KACT, k = idx % KACT;
    int j = j0 + r;
    wt[r][k] = (k < E_) ? w_ih[j*E_ + k] : w_hh[j*H2_ + (k - E_)];
  }
  __syncthreads();
  int jq = t >> 7, b = t & 127;
  float acc[4] = {0.f,0.f,0.f,0.f};
  for (int k = 0; k < KACT; ++k) {
    float a = act[k*B_ + b];
    #pragma unroll
    for (int jj = 0; jj < 4; ++jj) acc[jj] += wt[jq*4+jj][k]*a;
  }
  #pragma unroll
  for (int jj = 0; jj < 4; ++jj) {
    int j = j0 + jq*4 + jj;
    gates[j*B_ + b] = acc[jj] + b_ih[j] + b_hh[j];
  }
}

// ---- K2: LSTM elementwise + hdot ----
__global__ __launch_bounds__(256) void k_lstm(const float* __restrict__ gates,
    const float* __restrict__ pre_c, const float* __restrict__ w_align,
    float* __restrict__ o_h, float* __restrict__ o_c,
    float* __restrict__ hc, float* __restrict__ hdot){
  __shared__ float red[256];
  int b = blockIdx.x, k = threadIdx.x;
  float i_ = gates[(0*H2_ + k)*B_ + b];
  float f_ = gates[(1*H2_ + k)*B_ + b];
  float g_ = gates[(2*H2_ + k)*B_ + b];
  float o_ = gates[(3*H2_ + k)*B_ + b];
  float c = sigmoidf_(f_)*pre_c[b*H2_ + k] + sigmoidf_(i_)*tanhf(g_);
  float h = sigmoidf_(o_)*tanhf(c);
  o_h[b*H2_ + k] = h;
  o_c[b*H2_ + k] = c;
  hc[k*B_ + b] = h;
  float s = blk_reduce_sum(h * w_align[H2_ + k], red);
  if (k == 0) hdot[b] = s;
}

// ---- K3a: scores, grid (8 chunks of 50, B) ----
__global__ __launch_bounds__(256) void k_scores(const float* __restrict__ enc,
    const float* __restrict__ cov, const float* __restrict__ w_align,
    const float* __restrict__ b_align, const float* __restrict__ hdot,
    const float* __restrict__ ab, float* __restrict__ sc){
  int b = blockIdx.y, c = blockIdx.x;
  int t = threadIdx.x, wave = t >> 6, lane = t & 63;
  float4 wa4 = *(const float4*)&w_align[lane*4];
  float hd = hdot[b], alpha = ab[0], beta = ab[1], ba = b_align[0];
  int t0 = c*50;
  for (int tt = t0 + wave; tt < t0 + 50; tt += 4) {
    const float4* ep = (const float4*)&enc[((size_t)b*T_ + tt)*H2_];
    float4 e4 = ep[lane];
    float d = e4.x*wa4.x + e4.y*wa4.y + e4.z*wa4.z + e4.w*wa4.w;
    #pragma unroll
    for (int m = 32; m >= 1; m >>= 1) d += __shfl_xor(d, m);
    if (lane == 0)
      sc[b*T_ + tt] = tanhf(d + hd + alpha*cov[b*T_ + tt] + beta + ba);
  }
}

// ---- K3b: softmax over T + scatter + newcov + covloss partial ----
__global__ __launch_bounds__(256) void k_soft(const float* __restrict__ sc_in,
    const float* __restrict__ cov, const int* __restrict__ src,
    float* __restrict__ o_attn, float* __restrict__ o_newcov,
    float* __restrict__ o_copy, float* __restrict__ covp,
    float* __restrict__ attn_ws){
  __shared__ float red[256];
  int b = blockIdx.x, t = threadIdx.x;
  float x1 = sc_in[b*T_ + t];
  float x2 = (t + 256 < T_) ? sc_in[b*T_ + t + 256] : -1e30f;
  float mx = blk_reduce_max(fmaxf(x1, x2), red);
  float e1 = __expf(x1 - mx);
  float e2 = (t + 256 < T_) ? __expf(x2 - mx) : 0.f;
  float sum = blk_reduce_sum(e1 + e2, red);
  float inv = 1.f/sum;
  float cl;
  {
    float a1 = e1*inv; float c1 = cov[b*T_ + t];
    attn_ws[b*T_ + t] = a1;
    o_attn[b*T_ + t] = a1;
    o_newcov[b*T_ + t] = c1 + a1;
    atomicAdd(&o_copy[(size_t)b*V_ + src[b*T_ + t]], a1);
    cl = fminf(a1, c1);
  }
  if (t + 256 < T_) {
    float a2 = e2*inv; float c2 = cov[b*T_ + t + 256];
    attn_ws[b*T_ + t + 256] = a2;
    o_attn[b*T_ + t + 256] = a2;
    o_newcov[b*T_ + t + 256] = c2 + a2;
    atomicAdd(&o_copy[(size_t)b*V_ + src[b*T_ + t + 256]], a2);
    cl += fminf(a2, c2);
  }
  float clsum = blk_reduce_sum(cl, red);
  if (t == 0) covp[b] = clsum;
}

// ---- K3c: context partials, grid (8 chunks, B) ----
__global__ __launch_bounds__(256) void k_ctx(const float* __restrict__ enc,
    const float* __restrict__ attn_ws, float* __restrict__ ctxp){
  __shared__ float a_s[50];
  int b = blockIdx.y, c = blockIdx.x, e = threadIdx.x;
  int t0 = c*50;
  if (e < 50) a_s[e] = attn_ws[b*T_ + t0 + e];
  __syncthreads();
  float acc = 0.f;
  #pragma unroll 5
  for (int i = 0; i < 50; ++i)
    acc += a_s[i] * enc[((size_t)b*T_ + t0 + i)*H2_ + e];
  ctxp[((size_t)b*8 + c)*H2_ + e] = acc;
}

// ---- K3d: context reduce + pgen ----
__global__ __launch_bounds__(256) void k_ctxpgen(const float* __restrict__ ctxp,
    const int* __restrict__ ids, const float* __restrict__ emb_table,
    const float* __restrict__ w_gen, const float* __restrict__ b_gen,
    float* __restrict__ hc, float* __restrict__ pgen){
  __shared__ float red[256];
  int b = blockIdx.x, t = threadIdx.x;
  float ctx = 0.f;
  #pragma unroll
  for (int c = 0; c < 8; ++c) ctx += ctxp[((size_t)b*8 + c)*H2_ + t];
  hc[(H2_ + t)*B_ + b] = ctx;
  float p = ctx*w_gen[t] + hc[t*B_ + b]*w_gen[H2_ + t];
  if (t < E_) p += emb_table[(size_t)ids[b]*E_ + t]*w_gen[2*H2_ + t];
  float s = blk_reduce_sum(p, red);
  if (t == 0) pgen[b] = sigmoidf_(s + b_gen[0]);
}

// ---- K4: fc1, output bf16 [b][k] ----
__global__ __launch_bounds__(256) void k_fc1(const float* __restrict__ hc,
    const float* __restrict__ w_fc1, const float* __restrict__ b_fc1,
    short* __restrict__ fcb){
  __shared__ float wt[16][H4_];
  int t = threadIdx.x; int j0 = blockIdx.x*16;
  for (int idx = t; idx < 16*H4_; idx += 256) {
    int r = idx >> 9, k = idx & 511;
    wt[r][k] = w_fc1[(j0 + r)*H4_ + k];
  }
  __syncthreads();
  int jq = t >> 7, b = t & 127;
  float acc[8] = {};
  for (int k = 0; k < H4_; ++k) {
    float a = hc[k*B_ + b];
    #pragma unroll
    for (int jj = 0; jj < 8; ++jj) acc[jj] += wt[jq*8+jj][k]*a;
  }
  bf16x8 pack;
  #pragma unroll
  for (int jj = 0; jj < 8; ++jj) {
    int j = j0 + jq*8 + jj;
    pack[jj] = f2bf(tanhf(acc[jj] + b_fc1[j]));
  }
  *(bf16x8*)&fcb[(size_t)b*H4_ + j0 + jq*8] = pack;
}

// ---- K5: MFMA 32x32x16 GEMM. logits[b][v] = fcb[b][:]·w_fc2[v][:] + b_fc2[v]
// 256 thr (4 waves), v-tile 128 (32 v/wave), fcb staged in 2 half-K LDS slabs.
#define KH 256
__global__ __launch_bounds__(256, 2) void k_gemm2m(const short* __restrict__ fcb,
    const float* __restrict__ w_fc2, const float* __restrict__ b_fc2,
    float* __restrict__ logits){
  __shared__ short lds[B_*KH];          // 64 KB, rows 512B, XOR-swizzled
  char* ldsb = (char*)lds;
  int t = threadIdx.x;
  int w = t >> 6, l = t & 63;
  int ln = l & 31, g2 = l >> 5;
  int v = blockIdx.x*128 + w*32 + ln;
  int vc = v < V_ ? v : V_ - 1;
  f32x16 acc0 = {}, acc1 = {}, acc2 = {}, acc3 = {};

  #pragma unroll
  for (int h = 0; h < 2; ++h) {
    int kb = h*KH;
    if (h) __syncthreads();             // all waves done reading slab 0
    // stage fcb[:, kb..kb+255] -> LDS (reg-staged, swizzled)
    #pragma unroll
    for (int r = 0; r < 16; ++r) {
      int lid = r*256 + t;
      int row = lid >> 5, cg = lid & 31;
      bf16x8 d = *(const bf16x8*)&fcb[row*H4_ + kb + cg*8];
      *(bf16x8*)(ldsb + row*512 + ((cg*16) ^ ((row & 7) << 4))) = d;
    }
    __syncthreads();

    const float* wrow = w_fc2 + (size_t)vc*H4_ + kb + g2*8;
    float4 a0,b0,a1,b1,a2,b2,a3,b3;
    #define LW(s, i) { a##s = *(const float4*)(wrow + (i)*16); \
                       b##s = *(const float4*)(wrow + (i)*16 + 4); }
    #define STEP(s, i)                                                        \
    {                                                                         \
      bf16x8 bf;                                                              \
      bf[0]=f2bf(a##s.x); bf[1]=f2bf(a##s.y); bf[2]=f2bf(a##s.z);             \
      bf[3]=f2bf(a##s.w); bf[4]=f2bf(b##s.x); bf[5]=f2bf(b##s.y);             \
      bf[6]=f2bf(b##s.z); bf[7]=f2bf(b##s.w);                                 \
      int kbyte = (i)*32 + g2*16;                                             \
      { int row = ln;                                                         \
        bf16x8 af = *(const bf16x8*)(ldsb + row*512 + (kbyte ^ ((row&7)<<4)));\
        acc0 = __builtin_amdgcn_mfma_f32_32x32x16_bf16(af, bf, acc0, 0,0,0); }\
      { int row = 32 + ln;                                                    \
        bf16x8 af = *(const bf16x8*)(ldsb + row*512 + (kbyte ^ ((row&7)<<4)));\
        acc1 = __builtin_amdgcn_mfma_f32_32x32x16_bf16(af, bf, acc1, 0,0,0); }\
      { int row = 64 + ln;                                                    \
        bf16x8 af = *(const bf16x8*)(ldsb + row*512 + (kbyte ^ ((row&7)<<4)));\
        acc2 = __builtin_amdgcn_mfma_f32_32x32x16_bf16(af, bf, acc2, 0,0,0); }\
      { int row = 96 + ln;                                                    \
        bf16x8 af = *(const bf16x8*)(ldsb + row*512 + (kbyte ^ ((row&7)<<4)));\
        acc3 = __builtin_amdgcn_mfma_f32_32x32x16_bf16(af, bf, acc3, 0,0,0); }\
    }
    LW(0,0) LW(1,1) LW(2,2) LW(3,3)
    STEP(0,0)  LW(0,4)
    STEP(1,1)  LW(1,5)
    STEP(2,2)  LW(2,6)
    STEP(3,3)  LW(3,7)
    STEP(0,4)  LW(0,8)
    STEP(1,5)  LW(1,9)
    STEP(2,6)  LW(2,10)
    STEP(3,7)  LW(3,11)
    STEP(0,8)  LW(0,12)
    STEP(1,9)  LW(1,13)
    STEP(2,10) LW(2,14)
    STEP(3,11) LW(3,15)
    STEP(0,12)
    STEP(1,13)
    STEP(2,14)
    STEP(3,15)
    #undef LW
    #undef STEP
  }

  if (v < V_) {
    float bias = b_fc2[v];
    #pragma unroll
    for (int r = 0; r < 16; ++r) {
      int brow = (r & 3) + 8*(r >> 2) + 4*g2;
      logits[(size_t)(brow)*V_ + v]      = acc0[r] + bias;
      logits[(size_t)(32 + brow)*V_ + v] = acc1[r] + bias;
      logits[(size_t)(64 + brow)*V_ + v] = acc2[r] + bias;
      logits[(size_t)(96 + brow)*V_ + v] = acc3[r] + bias;
    }
  }
}

// ---- K6a: softmax partial stats, grid (8, B) ----
__global__ __launch_bounds__(256) void k_smp(const float* __restrict__ logits,
    float* __restrict__ smp){
  __shared__ float rm[256], rs[256];
  int b = blockIdx.y, c = blockIdx.x, t = threadIdx.x;
  int v0 = c*6250, v1 = v0 + 6250;
  float m = -1e30f, s = 0.f;
  for (int v = v0 + t; v < v1; v += 256) {
    float x = logits[(size_t)b*V_ + v];
    float nm = fmaxf(m, x);
    s = s*__expf(m - nm) + __expf(x - nm);
    m = nm;
  }
  rm[t] = m; rs[t] = s; __syncthreads();
  for (int k = 128; k > 0; k >>= 1) {
    if (t < k) {
      float m1 = rm[t], s1 = rs[t], m2 = rm[t+k], s2 = rs[t+k];
      float nm = fmaxf(m1, m2);
      rm[t] = nm; rs[t] = s1*__expf(m1-nm) + s2*__expf(m2-nm);
    }
    __syncthreads();
  }
  if (t == 0) { smp[(b*8+c)*2] = rm[0]; smp[(b*8+c)*2+1] = rs[0]; }
}

// ---- K6b: combine stats + covloss ----
__global__ __launch_bounds__(128) void k_smred_cl(const float* __restrict__ smp,
    const float* __restrict__ covp, float* __restrict__ mx,
    float* __restrict__ inv, float* __restrict__ o_cl){
  __shared__ float red[128];
  int t = threadIdx.x;
  float m = -1e30f, s = 0.f;
  #pragma unroll
  for (int c = 0; c < 8; ++c) {
    float m2 = smp[(t*8+c)*2], s2 = smp[(t*8+c)*2+1];
    float nm = fmaxf(m, m2);
    s = s*__expf(m - nm) + s2*__expf(m2 - nm);
    m = nm;
  }
  mx[t] = m; inv[t] = 1.f/s;
  red[t] = covp[t]; __syncthreads();
  for (int k = 64; k > 0; k >>= 1){ if (t < k) red[t] += red[t+k]; __syncthreads(); }
  if (t == 0) o_cl[0] = red[0];
}

// ---- K7: final mix (float4) ----
__global__ __launch_bounds__(256) void k_final(const float* __restrict__ copy,
    const float* __restrict__ mx, const float* __restrict__ inv_s,
    const float* __restrict__ pgen, float* __restrict__ out){
  size_t gid = (size_t)blockIdx.x*256 + threadIdx.x;
  int b = (int)(gid / (V_/4));
  int v = (int)(gid % (V_/4))*4;
  size_t idx = (size_t)b*V_ + v;
  float m = mx[b], is = inv_s[b], pg = pgen[b];
  float4 lg = *(const float4*)&out[idx];
  float4 cp = *(const float4*)&copy[idx];
  float4 o;
  o.x = __expf(lg.x - m)*is*pg + cp.x*(1.f - pg);
  o.y = __expf(lg.y - m)*is*pg + cp.y*(1.f - pg);
  o.z = __expf(lg.z - m)*is*pg + cp.z*(1.f - pg);
  o.w = __expf(lg.w - m)*is*pg + cp.w*(1.f - pg);
  *(float4*)&out[idx] = o;
}

extern "C" void kernel_launch(void* const* d_in, const int* in_sizes, int n_in,
                              void* d_out, int out_size, void* d_ws, size_t ws_size,
                              hipStream_t stream) {
  const int*   ids       = (const int*)  d_in[0];
  const float* pre_h     = (const float*)d_in[1];
  const float* pre_c     = (const float*)d_in[2];
  const float* enc       = (const float*)d_in[3];
  const int*   src       = (const int*)  d_in[4];
  const float* cov       = (const float*)d_in[5];
  const float* emb_table = (const float*)d_in[6];
  const float* w_ih      = (const float*)d_in[7];
  const float* w_hh      = (const float*)d_in[8];
  const float* b_ih      = (const float*)d_in[9];
  const float* b_hh      = (const float*)d_in[10];
  const float* w_align   = (const float*)d_in[11];
  const float* b_align   = (const float*)d_in[12];
  const float* w_cov     = (const float*)d_in[13];
  const float* b_cov     = (const float*)d_in[14];
  const float* w_fc1     = (const float*)d_in[15];
  const float* b_fc1     = (const float*)d_in[16];
  const float* w_fc2     = (const float*)d_in[17];
  const float* b_fc2     = (const float*)d_in[18];
  const float* w_gen     = (const float*)d_in[19];
  const float* b_gen     = (const float*)d_in[20];

  float* out = (float*)d_out;
  float* ws  = (float*)d_ws;

  float* o_out    = out;
  float* o_h      = out + OFF_H;
  float* o_c      = out + OFF_C;
  float* o_attn   = out + OFF_ATTN;
  float* o_copy   = out + OFF_COPY;
  float* o_newcov = out + OFF_NEWCOV;
  float* o_cl     = out + OFF_COVLOSS;

  k_zero <<<(B_*V_/4 + 255)/256, 256, 0, stream>>>(o_copy);
  k_act  <<<192, 256, 0, stream>>>(ids, pre_h, emb_table, w_align, w_cov, b_cov,
                                   ws + WS_ACT, ws + WS_AB);
  k_gates<<<128, 256, 0, stream>>>(ws + WS_ACT, w_ih, w_hh, b_ih, b_hh, ws + WS_GATES);
  k_lstm <<<128, 256, 0, stream>>>(ws + WS_GATES, pre_c, w_align, o_h, o_c,
                                   ws + WS_HC, ws + WS_HDOT);
  k_scores<<<dim3(8,128), 256, 0, stream>>>(enc, cov, w_align, b_align,
                                   ws + WS_HDOT, ws + WS_AB, ws + WS_SC);
  k_soft <<<128, 256, 0, stream>>>(ws + WS_SC, cov, src, o_attn, o_newcov, o_copy,
                                   ws + WS_COVP, ws + WS_ATTN);
  k_ctx  <<<dim3(8,128), 256, 0, stream>>>(enc, ws + WS_ATTN, ws + WS_CTXP);
  k_ctxpgen<<<128, 256, 0, stream>>>(ws + WS_CTXP, ids, emb_table, w_gen, b_gen,
                                   ws + WS_HC, ws + WS_PGEN);
  k_fc1  <<<32, 256, 0, stream>>>(ws + WS_HC, w_fc1, b_fc1, (short*)(ws + WS_FCB));
  k_gemm2m<<<(V_ + 127)/128, 256, 0, stream>>>((const short*)(ws + WS_FCB),
                                   w_fc2, b_fc2, o_out);
  k_smp  <<<dim3(8,128), 256, 0, stream>>>(o_out, ws + WS_SMP);
  k_smred_cl<<<1, 128, 0, stream>>>(ws + WS_SMP, ws + WS_COVP,
                                   ws + WS_MAX, ws + WS_INV, o_cl);
  k_final<<<(int)(((size_t)B_*V_/4)/256), 256, 0, stream>>>(
      o_copy, ws + WS_MAX, ws + WS_INV, ws + WS_PGEN, o_out);
}